// Round 8
// baseline (607.824 us; speedup 1.0000x reference)
//
#include <hip/hip_runtime.h>
#include <hip/hip_bf16.h>
#include <hip/hip_fp16.h>

// Inputs/outputs are FP32 (verified R3/R6).
// R10 lesson: KV-in-regs OR weights-in-regs — never both (VGPR cap -> compiler demotes).
// R11 lesson: redundant all-wave broadcast stages LOSE (4x LDS traffic > 3 barriers).
// R12 lesson: v_dot2 + fp16 LDS cut k_dec 450->335; chain is latency-bound.
// R13 lesson: wall time = per-step CRITICAL PATH (blocks already concurrent).
// R14 lesson: mega-wave0 segments + 2 barriers/step -> 236us.
// R15 lesson: weights-in-VGPR regressed (compiler demoted; scratch > LDS).
// R16 lesson: launch gap ~10us/kernel measured (embed fusion: -12us total, -3 k_dec).
// R17: (1) encoder mega-fusion k_oproj_ln+k_ffn_ln+k_ckv -> k_post (2 fewer
//   launches, ~38MB less global traffic, LN1-out/mem never leave LDS);
//   (2) k_dec cross-o-proj as per-wave PARTIALS before B2 (poS[4][48]); after
//   the barrier wave0 does 4 reads + 3 adds instead of dot48 (~150cy off chain).

constexpr int kB  = 128;
constexpr int kS  = 512;
constexpr int kT  = 64;
constexpr int kD  = 48;
constexpr int kFF = 128;
constexpr int kNH = 4;
constexpr int kHD = 12;

__device__ __forceinline__ void wsync(){
  __builtin_amdgcn_wave_barrier();
  asm volatile("" ::: "memory");
}

// ---- DPP wave64 reductions (VALU-speed) ----
template<int CTRL,int RM,int BM,bool BC>
__device__ __forceinline__ float dppmov(float x, float old){
  return __builtin_bit_cast(float, __builtin_amdgcn_update_dpp(
      __builtin_bit_cast(int, old), __builtin_bit_cast(int, x), CTRL, RM, BM, BC));
}
// sum across 64 lanes, result uniform in all lanes
__device__ __forceinline__ float wsum(float x){
  x += dppmov<0x111,0xf,0xf,true>(x, 0.f);   // row_shr:1
  x += dppmov<0x112,0xf,0xf,true>(x, 0.f);   // row_shr:2
  x += dppmov<0x114,0xf,0xf,true>(x, 0.f);   // row_shr:4
  x += dppmov<0x118,0xf,0xf,true>(x, 0.f);   // row_shr:8
  x += dppmov<0x142,0xa,0xf,true>(x, 0.f);   // row_bcast:15 -> rows 1,3
  x += dppmov<0x143,0xc,0xf,true>(x, 0.f);   // row_bcast:31 -> rows 2,3
  return __builtin_bit_cast(float, __builtin_amdgcn_readlane(__builtin_bit_cast(int, x), 63));
}
// sum within each 16-lane row; result valid at lane 15 of each row
__device__ __forceinline__ float rowsum16(float x){
  x += dppmov<0x111,0xf,0xf,true>(x, 0.f);
  x += dppmov<0x112,0xf,0xf,true>(x, 0.f);
  x += dppmov<0x114,0xf,0xf,true>(x, 0.f);
  x += dppmov<0x118,0xf,0xf,true>(x, 0.f);
  return x;
}

// pe[p, 2i] = sin(p * exp(-2i*ln(10000)/48)), pe[p, 2i+1] = cos(...)
__device__ __forceinline__ float pe_val(int p, int j){   // precise (table init)
  int i = j >> 1;
  float f = expf(-0.19188209108283716f * (float)(2*i));
  float a = (float)p * f;
  return (j & 1) ? cosf(a) : sinf(a);
}
__device__ __forceinline__ float pe_fast(int p, int j){  // encoder embed
  int i = j >> 1;
  float f = __expf(-0.19188209108283716f * (float)(2*i));
  float a = (float)p * f;
  return (j & 1) ? __cosf(a) : __sinf(a);
}

// ---- packed fp16 dot: d = a.x*b.x + a.y*b.y + c (v_dot2_f32_f16) ----
typedef _Float16 h2v __attribute__((ext_vector_type(2)));
union H2U { __half2 h; h2v v; };
__device__ __forceinline__ float fdot2(__half2 a, __half2 b, float c){
#if __has_builtin(__builtin_amdgcn_fdot2)
  H2U ua, ub; ua.h=a; ub.h=b;
  return __builtin_amdgcn_fdot2(ua.v, ub.v, c, false);
#else
  float2 fa=__half22float2(a), fb=__half22float2(b);
  return fmaf(fa.y, fb.y, fmaf(fa.x, fb.x, c));
#endif
}

// 48-dot, x (LDS or reg array) vs w (LDS), 4 accumulator chains
__device__ __forceinline__ float dot48d(const __half2* x, const __half* w){
  const __half2* w2=(const __half2*)w;
  float a0=0.f,a1=0.f,a2=0.f,a3=0.f;
  #pragma unroll
  for(int c=0;c<6;c++){
    a0=fdot2(x[4*c+0],w2[4*c+0],a0);
    a1=fdot2(x[4*c+1],w2[4*c+1],a1);
    a2=fdot2(x[4*c+2],w2[4*c+2],a2);
    a3=fdot2(x[4*c+3],w2[4*c+3],a3);
  }
  return (a0+a1)+(a2+a3);
}
// 128-dot, 8 accumulator chains
__device__ __forceinline__ float dot128d(const __half2* x, const __half* w){
  const __half2* w2=(const __half2*)w;
  float a0=0.f,a1=0.f,a2=0.f,a3=0.f,a4=0.f,a5=0.f,a6=0.f,a7=0.f;
  #pragma unroll
  for(int c=0;c<8;c++){
    a0=fdot2(x[8*c+0],w2[8*c+0],a0);
    a1=fdot2(x[8*c+1],w2[8*c+1],a1);
    a2=fdot2(x[8*c+2],w2[8*c+2],a2);
    a3=fdot2(x[8*c+3],w2[8*c+3],a3);
    a4=fdot2(x[8*c+4],w2[8*c+4],a4);
    a5=fdot2(x[8*c+5],w2[8*c+5],a5);
    a6=fdot2(x[8*c+6],w2[8*c+6],a6);
    a7=fdot2(x[8*c+7],w2[8*c+7],a7);
  }
  return ((a0+a1)+(a2+a3))+((a4+a5)+(a6+a7));
}

// ---------------- K2: FUSED embed + encoder QKV projection ----------------
__global__ void __launch_bounds__(256) k_qkv(const float* __restrict__ src,
    const float* __restrict__ in_w, const float* __restrict__ in_b,
    float* __restrict__ X0,
    const float* __restrict__ wq, const float* __restrict__ bq,
    const float* __restrict__ wk, const float* __restrict__ bk,
    const float* __restrict__ wv, const float* __restrict__ bv,
    __half* __restrict__ Q, __half* __restrict__ K, __half* __restrict__ V){
  __shared__ __align__(16) __half W[3*2688];     // col stride 56 halves
  __shared__ __align__(16) float bias[3*kD];
  __shared__ __align__(16) __half2 xt2[32*24];
  int tid = threadIdx.x;
  for (int i=tid;i<3*2304;i+=256){ int m=i/2304, e=i%2304, k=e/48, j=e%48;
    const float* w = (m==0)?wq:((m==1)?wk:wv);
    W[m*2688 + j*56 + k] = __float2half(w[e]); }
  for (int i=tid;i<3*kD;i+=256){ int m=i/kD,e=i%kD;
    const float* w=(m==0)?bq:((m==1)?bk:bv); bias[i]=w[e]; }
  long row0 = (long)blockIdx.x*32;
  const float sc = 6.928203230275509f;
  // fused embed: x = (src*in_w+in_b)*sqrt(d) + pe; fp32 -> X0, fp16 -> LDS
  for (int i=tid;i<768;i+=256){
    int r=i/24, c=i%24;
    long gr=row0+r; int s=(int)(gr&511);
    float sv=src[gr];
    float va=(sv*in_w[2*c  ]+in_b[2*c  ])*sc + pe_fast(s,2*c  );
    float vb=(sv*in_w[2*c+1]+in_b[2*c+1])*sc + pe_fast(s,2*c+1);
    ((float2*)X0)[row0*24 + i]=make_float2(va,vb);
    xt2[i]=__floats2half2_rn(va,vb);
  }
  __syncthreads();
  int r = tid>>3, c0 = tid&7;
  __half2 xr[24];
  #pragma unroll
  for(int u=0;u<24;u++) xr[u]=xt2[r*24+u];
  for (int c=c0; c<3*kD; c+=8){
    int m=c/kD, j=c%kD;
    float acc = bias[m*kD+j] + dot48d(xr, W + m*2688 + j*56);
    __half* o = (m==0)?Q:((m==1)?K:V);
    o[(row0+r)*kD+j]=__float2half(acc);
  }
}

// ---------------- K3: encoder attention — dot2 scores, float2 (pk) PV acc ----------------
__global__ void __launch_bounds__(256) k_attn(const __half* Q, const __half* __restrict__ K,
                       const __half* __restrict__ V, __half* O){
  int b = blockIdx.x / kNH, h = blockIdx.x % kNH;
  __shared__ __align__(16) __half2 Ks2[kS*6];  // 12 KB
  __shared__ __align__(16) float   Vs[kS*kHD]; // 24 KB (fp32: P stays fp32, no overflow)
  int tid = threadIdx.x;
  long base = ((long)b*kS)*kD + h*kHD;
  for (int i=tid;i<kS*6;i+=256){ int r=i/6, c=i%6;
    Ks2[i]=*(const __half2*)&K[base+(long)r*kD+2*c]; }
  for (int i=tid;i<kS*kHD;i+=256){ int r=i/kHD, d=i%kHD;
    Vs[i]=__half2float(V[base+(long)r*kD+d]); }
  const float rs = 0.28867513459481287f;
  int q0 = tid, q1 = tid+256;
  __half2 qa2[6], qb2[6];
  {
    const __half2* qp0=(const __half2*)(Q+base+(long)q0*kD);
    const __half2* qp1=(const __half2*)(Q+base+(long)q1*kD);
    #pragma unroll
    for(int c=0;c<6;c++){ qa2[c]=qp0[c]; qb2[c]=qp1[c]; }
  }
  __syncthreads();
  float2 acc0[6], acc1[6];
  #pragma unroll
  for(int j=0;j<6;j++){ acc0[j]=make_float2(0.f,0.f); acc1[j]=make_float2(0.f,0.f); }
  float l0=0.f, l1=0.f;
  for(int k=0;k<kS;k++){
    const __half2* kp=Ks2+k*6;
    float sA0=0.f,sA1=0.f,sB0=0.f,sB1=0.f;
    #pragma unroll
    for(int c=0;c<3;c++){
      sA0=fdot2(qa2[2*c],kp[2*c],sA0); sA1=fdot2(qa2[2*c+1],kp[2*c+1],sA1);
      sB0=fdot2(qb2[2*c],kp[2*c],sB0); sB1=fdot2(qb2[2*c+1],kp[2*c+1],sB1);
    }
    float p0=__expf((sA0+sA1)*rs), p1=__expf((sB0+sB1)*rs);
    l0+=p0; l1+=p1;
    const float2* vp=(const float2*)(Vs+k*kHD);
    #pragma unroll
    for(int j=0;j<6;j++){
      float2 v=vp[j];
      acc0[j].x=fmaf(p0,v.x,acc0[j].x); acc0[j].y=fmaf(p0,v.y,acc0[j].y);
      acc1[j].x=fmaf(p1,v.x,acc1[j].x); acc1[j].y=fmaf(p1,v.y,acc1[j].y);
    }
  }
  float i0=1.f/l0, i1=1.f/l1;
  #pragma unroll
  for(int j=0;j<6;j++){
    O[base+(long)q0*kD+2*j  ]=__float2half(acc0[j].x*i0);
    O[base+(long)q0*kD+2*j+1]=__float2half(acc0[j].y*i0);
    O[base+(long)q1*kD+2*j  ]=__float2half(acc1[j].x*i1);
    O[base+(long)q1*kD+2*j+1]=__float2half(acc1[j].y*i1);
  }
}

// ---------------- K4: FUSED o-proj+LN1 + FFN+LN2 + cross-K/V projection ----------------
// LN1-out and mem never leave LDS; writes only Kc [b][s][d] and Vc [b][d][s].
__global__ void __launch_bounds__(256) k_post(
    const float* __restrict__ Xres, const __half* __restrict__ O,
    const float* __restrict__ wo, const float* __restrict__ bo,
    const float* __restrict__ g1, const float* __restrict__ b1ln,
    const float* __restrict__ w1, const float* __restrict__ b1,
    const float* __restrict__ w2, const float* __restrict__ b2,
    const float* __restrict__ g2, const float* __restrict__ b2ln,
    const float* __restrict__ wk, const float* __restrict__ bk,
    const float* __restrict__ wv, const float* __restrict__ bv,
    __half* __restrict__ Kc, __half* __restrict__ Vc){
  __shared__ __align__(16) __half Wo[2688];      // 48 cols, stride 56
  __shared__ __align__(16) __half W1[7168];      // 128 cols, stride 56
  __shared__ __align__(16) __half W2[6528];      // 48 cols, stride 136
  __shared__ __align__(16) __half Wk[2688], Wv[2688];
  __shared__ float bos[kD], g1s[kD], b1lns[kD], b1s[kFF], b2s[kD],
                   g2s[kD], b2lns[kD], bks[kD], bvs[kD];
  __shared__ __align__(16) __half2 ot2[16*24];
  __shared__ __align__(16) float res[16*kD];
  __shared__ __align__(16) __half xt[16*kD];     // LN1 out (fp16, LDS-only)
  __shared__ __align__(16) __half h1h[16*kFF];
  __shared__ __align__(16) float res2[16*kD];
  __shared__ __align__(16) __half memh[16*kD];   // LN2 out (fp16, LDS-only)
  __shared__ float mrow[16], rstd[16];
  int tid=threadIdx.x;
  for(int i=tid;i<2304;i+=256){ int k=i/48, j=i%48; Wo[j*56+k]=__float2half(wo[i]); }
  for(int i=tid;i<kD*kFF;i+=256){ int k=i/128, c=i%128; W1[c*56+k]=__float2half(w1[i]); }
  for(int i=tid;i<kFF*kD;i+=256){ int u=i/48, j=i%48; W2[j*136+u]=__float2half(w2[i]); }
  for(int i=tid;i<2304;i+=256){ int k=i/48, j=i%48;
    Wk[j*56+k]=__float2half(wk[i]); Wv[j*56+k]=__float2half(wv[i]); }
  if(tid<kD){ bos[tid]=bo[tid]; g1s[tid]=g1[tid]; b1lns[tid]=b1ln[tid];
    b2s[tid]=b2[tid]; g2s[tid]=g2[tid]; b2lns[tid]=b2ln[tid];
    bks[tid]=bk[tid]; bvs[tid]=bv[tid]; }
  if(tid<kFF) b1s[tid]=b1[tid];
  long row0=(long)blockIdx.x*16;
  const __half2* Op=(const __half2*)(O+row0*kD);
  for(int i=tid;i<384;i+=256) ot2[i]=Op[i];
  __syncthreads();
  int r=tid>>4, c0=tid&15;
  // oproj + residual
  {
    __half2 orow[24];
    #pragma unroll
    for(int u=0;u<24;u++) orow[u]=ot2[r*24+u];
    for(int j=c0;j<kD;j+=16){
      float acc=bos[j]+dot48d(orow, Wo+j*56);
      res[r*kD+j]=Xres[row0*kD + r*kD + j]+acc;
    }
  }
  __syncthreads();
  if(tid<16){
    float s=0.f, s2=0.f;
    for(int j=0;j<kD;j++){ float v=res[tid*kD+j]; s+=v; s2+=v*v; }
    float m=s*(1.f/kD);
    mrow[tid]=m; rstd[tid]=rsqrtf(s2*(1.f/kD)-m*m+1e-5f);
  }
  __syncthreads();
  for(int i=tid;i<16*kD;i+=256){int r2=i/kD,j=i%kD;
    xt[i]=__float2half((res[i]-mrow[r2])*rstd[r2]*g1s[j]+b1lns[j]); }
  __syncthreads();
  // FFN1
  {
    __half2 xr[24];
    const __half2* xp=(const __half2*)(xt + r*kD);
    #pragma unroll
    for(int u=0;u<24;u++) xr[u]=xp[u];
    for(int c=c0;c<kFF;c+=16){
      float acc=b1s[c]+dot48d(xr, W1+c*56);
      h1h[r*kFF+c]=__float2half(fmaxf(acc,0.f));
    }
  }
  __syncthreads();
  // FFN2 + residual
  {
    const __half2* hp=(const __half2*)(h1h + r*kFF);
    for(int j=c0;j<kD;j+=16){
      float acc=b2s[j]+dot128d(hp, W2+j*136);
      res2[r*kD+j]=__half2float(xt[r*kD+j])+acc;
    }
  }
  __syncthreads();
  if(tid<16){
    float s=0.f, s2=0.f;
    for(int j=0;j<kD;j++){ float v=res2[tid*kD+j]; s+=v; s2+=v*v; }
    float m=s*(1.f/kD);
    mrow[tid]=m; rstd[tid]=rsqrtf(s2*(1.f/kD)-m*m+1e-5f);
  }
  __syncthreads();
  for(int i=tid;i<16*kD;i+=256){int r2=i/kD,j=i%kD;
    memh[i]=__float2half((res2[i]-mrow[r2])*rstd[r2]*g2s[j]+b2lns[j]); }
  __syncthreads();
  // cross K/V projection from memh
  {
    __half2 mr[24];
    const __half2* mp=(const __half2*)(memh + r*kD);
    #pragma unroll
    for(int u=0;u<24;u++) mr[u]=mp[u];
    long gr=row0+r; long bb2=gr>>9; long s=gr&511;
    for(int c=c0;c<2*kD;c+=16){
      int m=c/kD, j=c%kD;
      float acc=(m?bvs:bks)[j]+dot48d(mr, (m?Wv:Wk)+j*56);
      if(m==0) Kc[(bb2*kS+s)*kD + j]=__float2half(acc);     // [b][s][d]
      else     Vc[(bb2*kD+j)*kS + s]=__float2half(acc);     // [b][d][s]
    }
  }
}

// ---------------- K0: decoder weights -> padded FP16, column-major ----------------
// Wh halves: 6 mats 48 cols stride 56: swq@0 swk@2688 swv@5376 swo@8064 cwq@10752
// cwo@13440; w1 128 cols stride 56 @16128; w2 48 cols stride 136 @23296. Tot 29824.
__global__ void k_prep(const float* __restrict__ swq,const float* __restrict__ swk,
                       const float* __restrict__ swv,const float* __restrict__ swo,
                       const float* __restrict__ cwq,const float* __restrict__ cwo,
                       const float* __restrict__ w1,const float* __restrict__ w2,
                       __half* __restrict__ Wh){
  int idx=blockIdx.x*256+threadIdx.x;
  if(idx>=26112) return;
  if(idx<13824){
    int m=idx/2304, e=idx%2304, j=e/48, k=e%48;
    const float* w = (m==0)?swq:((m==1)?swk:((m==2)?swv:((m==3)?swo:((m==4)?cwq:cwo))));
    Wh[m*2688 + j*56 + k] = __float2half(w[k*48+j]);
  } else if(idx<19968){
    int e=idx-13824, c=e/48, k=e%48;
    Wh[16128 + c*56 + k] = __float2half(w1[k*128+c]);
  } else {
    int e=idx-19968, j=e/128, u=e%128;
    Wh[23296 + j*136 + u] = __float2half(w2[u*48+j]);
  }
}

// ---------------- K7: decoder — R17: R16 + per-wave cross-o-proj partials ----------------
struct DecP {
  const float *dec_start, *sbq, *sbk, *sbv, *sbo, *ln1g, *ln1b,
              *cbq, *cbo, *ln2g, *ln2b, *fb1, *fb2, *ln3g, *ln3b, *ow, *ob;
};

__global__ void __launch_bounds__(256,1) k_dec(const __half* __restrict__ KT,
    const __half* __restrict__ VT, const __half* __restrict__ Wg, DecP P,
    float* __restrict__ out){
  __shared__ __align__(16) __half Wl[29824];       // fp16 weights, 58.25 KB
  __shared__ __align__(16) float peT[kT*kD];       // PE table, 12 KB
  __shared__ __align__(16) __half KhH[kNH*kT*kHD]; // self-K cache fp16, 6 KB
  __shared__ __align__(16) float  Vh[kNH*kT*kHD];  // self-V cache fp32, 12 KB
  __shared__ __align__(16) __half qSH[kNH*kHD];    // q by head, fp16
  __shared__ __align__(16) float poS[kNH][kD];     // per-wave cross-o-proj partials
  __shared__ __align__(16) __half xvH[kD], soH[kD], h1H[kD], cqH[kD], h2H[kD];
  __shared__ __align__(16) __half f1H[kFF];
  int tid=threadIdx.x, b=blockIdx.x, wave=tid>>6, lane=tid&63;
  const float rs=0.28867513459481287f;

  for(int i=tid;i<29824/8;i+=256) ((float4*)Wl)[i]=((const float4*)Wg)[i];
  for(int i=tid;i<kT*kD;i+=256){ int tt=i/kD, j=i%kD; peT[i]=pe_val(tt,j); }

  // wave0 per-lane constants (wave0 runs every stage except cross-attn)
  float c_sbq=0,c_sbk=0,c_sbv=0, c_bo=0,c_cbq=0,c_cbo=0,c_fb2=0;
  float g1=0,bb1=0,g2=0,bb2=0,g3=0,bb3=0,c_ow=0, c_fb1a=0,c_fb1b=0, c_ds=0;
  if(wave==0){
    if(lane<kD){
      c_ds=P.dec_start[lane];
      c_sbq=P.sbq[lane]; c_sbk=P.sbk[lane]; c_sbv=P.sbv[lane];
      c_bo=P.sbo[lane]; c_cbq=P.cbq[lane]; c_cbo=P.cbo[lane]; c_fb2=P.fb2[lane];
      g1=P.ln1g[lane]; bb1=P.ln1b[lane];
      g2=P.ln2g[lane]; bb2=P.ln2b[lane];
      g3=P.ln3g[lane]; bb3=P.ln3b[lane];
      c_ow=P.ow[lane];
    }
    c_fb1a=P.fb1[lane]; c_fb1b=P.fb1[lane+64];
  }
  float c_ob=P.ob[0];

  // cross-attn K/V resident in registers: head = wave, 4 key-PAIRS per lane
  // Kc layout [b][s][d]; Vc layout [b][d][s] read as half2 pairs along s.
  __half2 Kr2[4][2][6], Vr2[4][kHD];   // 48 + 48 VGPRs
  {
    const __half* Kb = KT + (long)b*kS*kD;
    const __half2* Vb = (const __half2*)VT + (long)b*kD*(kS/2);
    #pragma unroll
    for(int i=0;i<4;i++){
      int sp = lane + 64*i;
      #pragma unroll
      for(int e=0;e<2;e++){
        const __half2* kp=(const __half2*)(Kb + (long)(2*sp+e)*kD + wave*kHD);
        #pragma unroll
        for(int c=0;c<6;c++) Kr2[i][e][c]=kp[c];
      }
      #pragma unroll
      for(int u=0;u<kHD;u++) Vr2[i][u]=Vb[(wave*kHD+u)*(kS/2)+sp];
    }
  }
  __syncthreads();

  // peel t=0's A0: wave0 publishes x0
  float xv=0;
  if(wave==0 && lane<kD){ xv=c_ds+peT[lane]; xvH[lane]=__float2half(xv); }
  __syncthreads();

  float h1=0, h2=0, yacc=0;
  for(int t=0;t<kT;t++){
    // ======== A: wave0-only segment (wsync handoffs, no block barriers) ========
    if(wave==0){
      // A1: qkv — x loaded into regs ONCE, reused across 3 dots
      if(lane<kD){
        __half2 xr[24];
        const __half2* xp=(const __half2*)xvH;
        #pragma unroll
        for(int u=0;u<24;u++) xr[u]=xp[u];
        float qv=c_sbq+dot48d(xr, Wl + 0*2688 + lane*56);
        float kv=c_sbk+dot48d(xr, Wl + 1*2688 + lane*56);
        float vv=c_sbv+dot48d(xr, Wl + 2*2688 + lane*56);
        int hh=lane/kHD, dd=lane%kHD;
        qSH[lane]=__float2half(qv);
        KhH[(hh*kT+t)*kHD+dd]=__float2half(kv);
        Vh[(hh*kT+t)*kHD+dd]=vv;
      }
      wsync();
      // A2: self-attn, 4 heads in one wave: lane = head*16 + keygroup
      {
        int hh=lane>>4, g=lane&15;
        __half2 q2[6];
        const __half2* qp=(const __half2*)qSH + hh*6;
        #pragma unroll
        for(int c=0;c<6;c++) q2[c]=qp[c];
        float l=0.f, acc[kHD];
        #pragma unroll
        for(int u=0;u<kHD;u++) acc[u]=0.f;
        #pragma unroll
        for(int kk=0;kk<4;kk++){
          int key=g+16*kk;
          if(key<=t){
            const __half2* kp=(const __half2*)KhH + (hh*kT+key)*6;
            float a0=0.f,a1=0.f;
            a0=fdot2(q2[0],kp[0],a0); a1=fdot2(q2[1],kp[1],a1);
            a0=fdot2(q2[2],kp[2],a0); a1=fdot2(q2[3],kp[3],a1);
            a0=fdot2(q2[4],kp[4],a0); a1=fdot2(q2[5],kp[5],a1);
            float p=__expf((a0+a1)*rs);
            l+=p;
            const float4* vp=(const float4*)(Vh+(hh*kT+key)*kHD);
            float4 v0=vp[0], v1=vp[1], v2=vp[2];
            float vr[kHD]={v0.x,v0.y,v0.z,v0.w,v1.x,v1.y,v1.z,v1.w,v2.x,v2.y,v2.z,v2.w};
            #pragma unroll
            for(int u=0;u<kHD;u++) acc[u]+=p*vr[u];
          }
        }
        l=rowsum16(l);
        #pragma unroll
        for(int u=0;u<kHD;u++) acc[u]=rowsum16(acc[u]);
        if(g==15){
          float inv=1.f/l;
          #pragma unroll
          for(int u=0;u<6;u++)
            ((__half2*)soH)[hh*6+u]=__floats2half2_rn(acc[2*u]*inv, acc[2*u+1]*inv);
        }
      }
      wsync();
      // A3: self o-proj + residual + LN1
      {
        float rr=0.f;
        if(lane<kD)
          rr=xv+c_bo+dot48d((const __half2*)soH, Wl+8064+lane*56);
        float s1=wsum(rr), s2=wsum(rr*rr);
        float mean=s1*(1.f/48.f);
        float rstd=rsqrtf(s2*(1.f/48.f)-mean*mean+1e-5f);
        h1=0;
        if(lane<kD){ h1=(rr-mean)*rstd*g1+bb1; h1H[lane]=__float2half(h1); }
      }
      wsync();
      // A4: cross-q
      if(lane<kD)
        cqH[lane]=__float2half(c_cbq+dot48d((const __half2*)h1H, Wl+10752+lane*56));
    }
    __syncthreads();                                   // B1: cqH -> all waves
    // ======== X: cross-attn on all 4 waves (head = wave); fp32 P, no max-sub;
    //             ends with per-wave PARTIAL cross-o-proj into poS ========
    {
      __half2 q2[6];
      #pragma unroll
      for(int c=0;c<6;c++) q2[c]=((const __half2*)cqH)[wave*6+c];
      float s[8];
      #pragma unroll
      for(int i=0;i<4;i++){
        #pragma unroll
        for(int e=0;e<2;e++){
          float a0=0.f,a1=0.f;
          const __half2* kp=Kr2[i][e];
          a0=fdot2(q2[0],kp[0],a0); a1=fdot2(q2[1],kp[1],a1);
          a0=fdot2(q2[2],kp[2],a0); a1=fdot2(q2[3],kp[3],a1);
          a0=fdot2(q2[4],kp[4],a0); a1=fdot2(q2[5],kp[5],a1);
          s[2*i+e]=(a0+a1)*rs;
        }
      }
      float p32[8], l=0.f;
      #pragma unroll
      for(int j=0;j<8;j++){ p32[j]=__expf(s[j]); l+=p32[j]; }
      l=wsum(l);
      float inv=1.f/l;
      __half2 ph[4];
      #pragma unroll
      for(int i=0;i<4;i++) ph[i]=__floats2half2_rn(p32[2*i]*inv, p32[2*i+1]*inv);
      float acc[kHD];
      #pragma unroll
      for(int u=0;u<kHD;u++) acc[u]=0.f;
      #pragma unroll
      for(int i=0;i<4;i++){
        #pragma unroll
        for(int u=0;u<kHD;u++) acc[u]=fdot2(ph[i],Vr2[i][u],acc[u]);
      }
      #pragma unroll
      for(int u=0;u<kHD;u++) acc[u]=wsum(acc[u]);
      // R17: partial o-proj for this head (moves dot-work BEFORE barrier B2)
      if(lane<kD){
        __half2 ah[6];
        #pragma unroll
        for(int u=0;u<6;u++) ah[u]=__floats2half2_rn(acc[2*u],acc[2*u+1]);
        const __half2* wp=(const __half2*)(Wl+13440+lane*56+wave*kHD);
        float p0=0.f,p1=0.f;
        p0=fdot2(ah[0],wp[0],p0); p1=fdot2(ah[1],wp[1],p1);
        p0=fdot2(ah[2],wp[2],p0); p1=fdot2(ah[3],wp[3],p1);
        p0=fdot2(ah[4],wp[4],p0); p1=fdot2(ah[5],wp[5],p1);
        poS[wave][lane]=p0+p1;
      }
    }
    __syncthreads();                                   // B2: poS -> wave0
    // ======== C: wave0-only segment ========
    if(wave==0){
      // C0: cross o-proj = sum of 4 per-head partials; + residual + LN2
      {
        float rr=0.f;
        if(lane<kD)
          rr=h1+c_cbo+((poS[0][lane]+poS[1][lane])+(poS[2][lane]+poS[3][lane]));
        float s1=wsum(rr), s2=wsum(rr*rr);
        float mean=s1*(1.f/48.f);
        float rstd=rsqrtf(s2*(1.f/48.f)-mean*mean+1e-5f);
        h2=0;
        if(lane<kD){ h2=(rr-mean)*rstd*g2+bb2; h2H[lane]=__float2half(h2); }
      }
      wsync();
      // C1: FFN1 — 2 cols per lane (pipelined)
      {
        float a=c_fb1a+dot48d((const __half2*)h2H, Wl+16128+lane*56);
        float bcol=c_fb1b+dot48d((const __half2*)h2H, Wl+16128+(lane+64)*56);
        f1H[lane]=__float2half(fmaxf(a,0.f));
        f1H[lane+64]=__float2half(fmaxf(bcol,0.f));
      }
      wsync();
      // C2: FFN2 + residual + LN3; fused next-x publish; y into reg buffer
      {
        float rr=0.f;
        if(lane<kD)
          rr=h2+c_fb2+dot128d((const __half2*)f1H, Wl+23296+lane*136);
        float s1=wsum(rr), s2=wsum(rr*rr);
        float mean=s1*(1.f/48.f);
        float rstd=rsqrtf(s2*(1.f/48.f)-mean*mean+1e-5f);
        float cv=0.f;
        if(lane<kD) cv=(rr-mean)*rstd*g3+bb3;
        // publish x_{t+1} FIRST (hides under the y-reduction)
        if(lane<kD && t+1<kT){ xv=cv+peT[(t+1)*kD+lane]; xvH[lane]=__float2half(xv); }
        wsync();
        float y=wsum(cv*c_ow);
        if(lane==t) yacc=y;
      }
    }
  }
  if(wave==0) out[(long)b*kT+lane]=yacc+c_ob;
}

extern "C" void kernel_launch(void* const* d_in, const int* in_sizes, int n_in,
                              void* d_out, int out_size, void* d_ws, size_t ws_size,
                              hipStream_t stream){
  // ws: Wh fp16 (reserve 65536 B), A fp32 NB, H1/H2/H3 fp16 NB each (~31.5 MiB).
  float* ws = (float*)d_ws;
  __half* Wh = (__half*)ws;
  const size_t NB = (size_t)kB*kS*kD;     // 3,145,728
  float*  A  = ws + 16384;
  __half* H1 = (__half*)(A + NB);
  __half* H2 = H1 + NB;
  __half* H3 = H2 + NB;

  // H1=Q -> attn-out; H2=K -> Kc; H3=V -> Vc
  k_qkv  <<<(kB*kS)/32,256,0,stream>>>((const float*)d_in[0],(const float*)d_in[1],(const float*)d_in[2],A,
                                       (const float*)d_in[4],(const float*)d_in[5],(const float*)d_in[6],
                                       (const float*)d_in[7],(const float*)d_in[8],(const float*)d_in[9],H1,H2,H3);
  k_attn <<<kB*kNH,256,0,stream>>>(H1,H2,H3,H1);
  k_post <<<(kB*kS)/16,256,0,stream>>>(A,H1,
                                       (const float*)d_in[10],(const float*)d_in[11],
                                       (const float*)d_in[12],(const float*)d_in[13],
                                       (const float*)d_in[14],(const float*)d_in[15],
                                       (const float*)d_in[16],(const float*)d_in[17],
                                       (const float*)d_in[18],(const float*)d_in[19],
                                       (const float*)d_in[32],(const float*)d_in[33],
                                       (const float*)d_in[34],(const float*)d_in[35],H2,H3);
  k_prep    <<<(26112+255)/256,256,0,stream>>>((const float*)d_in[20],(const float*)d_in[22],(const float*)d_in[24],
                                               (const float*)d_in[26],(const float*)d_in[30],(const float*)d_in[36],
                                               (const float*)d_in[40],(const float*)d_in[42],Wh);
  DecP P;
  P.dec_start=(const float*)d_in[3];
  P.sbq=(const float*)d_in[21]; P.sbk=(const float*)d_in[23]; P.sbv=(const float*)d_in[25]; P.sbo=(const float*)d_in[27];
  P.ln1g=(const float*)d_in[28]; P.ln1b=(const float*)d_in[29];
  P.cbq=(const float*)d_in[31]; P.cbo=(const float*)d_in[37];
  P.ln2g=(const float*)d_in[38]; P.ln2b=(const float*)d_in[39];
  P.fb1=(const float*)d_in[41]; P.fb2=(const float*)d_in[43];
  P.ln3g=(const float*)d_in[44]; P.ln3b=(const float*)d_in[45];
  P.ow=(const float*)d_in[46]; P.ob=(const float*)d_in[47];
  k_dec<<<kB,256,0,stream>>>(H2,H3,Wh,P,(float*)d_out);
}

// Round 9
// 571.311 us; speedup vs baseline: 1.0639x; 1.0639x over previous
//
#include <hip/hip_runtime.h>
#include <hip/hip_bf16.h>
#include <hip/hip_fp16.h>

// Inputs/outputs are FP32 (verified R3/R6).
// R10: KV-in-regs OR weights-in-regs — never both (compiler demotes silently).
// R11: redundant all-wave broadcast stages LOSE. R12: dot2+fp16 LDS; latency-bound.
// R13: wall time = per-step critical path. R14: mega-wave0 + 2 barriers -> 236us.
// R15: weights-in-VGPR regressed. R16: launch gap ~10us/kernel; embed fusion ok.
// R17 lesson: encoder mega-fusion REGRESSED (-50us: staging/row 984->1200, 8-barrier
//   serial chain); k_dec cross-o-proj partials WON (233->230). 
// R18: revert fusion (R16 encoder); keep R17 k_dec; SPLIT k_attn 2-way over keys
//   (1024 blocks, 256-key serial chain, self-normalized fp16 partials + fp32 l);
//   exact merge fused into k_oproj_ln staging.

constexpr int kB  = 128;
constexpr int kS  = 512;
constexpr int kT  = 64;
constexpr int kD  = 48;
constexpr int kFF = 128;
constexpr int kNH = 4;
constexpr int kHD = 12;

__device__ __forceinline__ void wsync(){
  __builtin_amdgcn_wave_barrier();
  asm volatile("" ::: "memory");
}

// ---- DPP wave64 reductions (VALU-speed) ----
template<int CTRL,int RM,int BM,bool BC>
__device__ __forceinline__ float dppmov(float x, float old){
  return __builtin_bit_cast(float, __builtin_amdgcn_update_dpp(
      __builtin_bit_cast(int, old), __builtin_bit_cast(int, x), CTRL, RM, BM, BC));
}
// sum across 64 lanes, result uniform in all lanes
__device__ __forceinline__ float wsum(float x){
  x += dppmov<0x111,0xf,0xf,true>(x, 0.f);   // row_shr:1
  x += dppmov<0x112,0xf,0xf,true>(x, 0.f);   // row_shr:2
  x += dppmov<0x114,0xf,0xf,true>(x, 0.f);   // row_shr:4
  x += dppmov<0x118,0xf,0xf,true>(x, 0.f);   // row_shr:8
  x += dppmov<0x142,0xa,0xf,true>(x, 0.f);   // row_bcast:15 -> rows 1,3
  x += dppmov<0x143,0xc,0xf,true>(x, 0.f);   // row_bcast:31 -> rows 2,3
  return __builtin_bit_cast(float, __builtin_amdgcn_readlane(__builtin_bit_cast(int, x), 63));
}
// sum within each 16-lane row; result valid at lane 15 of each row
__device__ __forceinline__ float rowsum16(float x){
  x += dppmov<0x111,0xf,0xf,true>(x, 0.f);
  x += dppmov<0x112,0xf,0xf,true>(x, 0.f);
  x += dppmov<0x114,0xf,0xf,true>(x, 0.f);
  x += dppmov<0x118,0xf,0xf,true>(x, 0.f);
  return x;
}

// pe[p, 2i] = sin(p * exp(-2i*ln(10000)/48)), pe[p, 2i+1] = cos(...)
__device__ __forceinline__ float pe_val(int p, int j){   // precise (table init)
  int i = j >> 1;
  float f = expf(-0.19188209108283716f * (float)(2*i));
  float a = (float)p * f;
  return (j & 1) ? cosf(a) : sinf(a);
}
__device__ __forceinline__ float pe_fast(int p, int j){  // encoder embed
  int i = j >> 1;
  float f = __expf(-0.19188209108283716f * (float)(2*i));
  float a = (float)p * f;
  return (j & 1) ? __cosf(a) : __sinf(a);
}

// ---- packed fp16 dot: d = a.x*b.x + a.y*b.y + c (v_dot2_f32_f16) ----
typedef _Float16 h2v __attribute__((ext_vector_type(2)));
union H2U { __half2 h; h2v v; };
__device__ __forceinline__ float fdot2(__half2 a, __half2 b, float c){
#if __has_builtin(__builtin_amdgcn_fdot2)
  H2U ua, ub; ua.h=a; ub.h=b;
  return __builtin_amdgcn_fdot2(ua.v, ub.v, c, false);
#else
  float2 fa=__half22float2(a), fb=__half22float2(b);
  return fmaf(fa.y, fb.y, fmaf(fa.x, fb.x, c));
#endif
}

// 48-dot, x (LDS or reg array) vs w (LDS), 4 accumulator chains
__device__ __forceinline__ float dot48d(const __half2* x, const __half* w){
  const __half2* w2=(const __half2*)w;
  float a0=0.f,a1=0.f,a2=0.f,a3=0.f;
  #pragma unroll
  for(int c=0;c<6;c++){
    a0=fdot2(x[4*c+0],w2[4*c+0],a0);
    a1=fdot2(x[4*c+1],w2[4*c+1],a1);
    a2=fdot2(x[4*c+2],w2[4*c+2],a2);
    a3=fdot2(x[4*c+3],w2[4*c+3],a3);
  }
  return (a0+a1)+(a2+a3);
}
// 128-dot, 8 accumulator chains
__device__ __forceinline__ float dot128d(const __half2* x, const __half* w){
  const __half2* w2=(const __half2*)w;
  float a0=0.f,a1=0.f,a2=0.f,a3=0.f,a4=0.f,a5=0.f,a6=0.f,a7=0.f;
  #pragma unroll
  for(int c=0;c<8;c++){
    a0=fdot2(x[8*c+0],w2[8*c+0],a0);
    a1=fdot2(x[8*c+1],w2[8*c+1],a1);
    a2=fdot2(x[8*c+2],w2[8*c+2],a2);
    a3=fdot2(x[8*c+3],w2[8*c+3],a3);
    a4=fdot2(x[8*c+4],w2[8*c+4],a4);
    a5=fdot2(x[8*c+5],w2[8*c+5],a5);
    a6=fdot2(x[8*c+6],w2[8*c+6],a6);
    a7=fdot2(x[8*c+7],w2[8*c+7],a7);
  }
  return ((a0+a1)+(a2+a3))+((a4+a5)+(a6+a7));
}

// ---------------- K2: FUSED embed + encoder QKV projection ----------------
__global__ void __launch_bounds__(256) k_qkv(const float* __restrict__ src,
    const float* __restrict__ in_w, const float* __restrict__ in_b,
    float* __restrict__ X0,
    const float* __restrict__ wq, const float* __restrict__ bq,
    const float* __restrict__ wk, const float* __restrict__ bk,
    const float* __restrict__ wv, const float* __restrict__ bv,
    __half* __restrict__ Q, __half* __restrict__ K, __half* __restrict__ V){
  __shared__ __align__(16) __half W[3*2688];     // col stride 56 halves
  __shared__ __align__(16) float bias[3*kD];
  __shared__ __align__(16) __half2 xt2[32*24];
  int tid = threadIdx.x;
  for (int i=tid;i<3*2304;i+=256){ int m=i/2304, e=i%2304, k=e/48, j=e%48;
    const float* w = (m==0)?wq:((m==1)?wk:wv);
    W[m*2688 + j*56 + k] = __float2half(w[e]); }
  for (int i=tid;i<3*kD;i+=256){ int m=i/kD,e=i%kD;
    const float* w=(m==0)?bq:((m==1)?bk:bv); bias[i]=w[e]; }
  long row0 = (long)blockIdx.x*32;
  const float sc = 6.928203230275509f;
  // fused embed: x = (src*in_w+in_b)*sqrt(d) + pe; fp32 -> X0, fp16 -> LDS
  for (int i=tid;i<768;i+=256){
    int r=i/24, c=i%24;
    long gr=row0+r; int s=(int)(gr&511);
    float sv=src[gr];
    float va=(sv*in_w[2*c  ]+in_b[2*c  ])*sc + pe_fast(s,2*c  );
    float vb=(sv*in_w[2*c+1]+in_b[2*c+1])*sc + pe_fast(s,2*c+1);
    ((float2*)X0)[row0*24 + i]=make_float2(va,vb);
    xt2[i]=__floats2half2_rn(va,vb);
  }
  __syncthreads();
  int r = tid>>3, c0 = tid&7;
  __half2 xr[24];
  #pragma unroll
  for(int u=0;u<24;u++) xr[u]=xt2[r*24+u];
  for (int c=c0; c<3*kD; c+=8){
    int m=c/kD, j=c%kD;
    float acc = bias[m*kD+j] + dot48d(xr, W + m*2688 + j*56);
    __half* o = (m==0)?Q:((m==1)?K:V);
    o[(row0+r)*kD+j]=__float2half(acc);
  }
}

// ---------------- K3: encoder attention — R18: 2-way KEY SPLIT ----------------
// grid 1024: blockIdx = (b*kNH+h)*2+part. Each block: 256 keys, self-normalized
// fp16 partial output + fp32 partial denominator. Merge happens in k_oproj_ln.
__global__ void __launch_bounds__(256) k_attn(const __half* __restrict__ Q,
      const __half* __restrict__ K, const __half* __restrict__ V,
      __half* __restrict__ OP, float* __restrict__ lP){
  int part = blockIdx.x & 1;
  int bh = blockIdx.x >> 1;
  int b = bh / kNH, h = bh % kNH;
  __shared__ __align__(16) __half2 Ks2[256*6];  // 6 KB
  __shared__ __align__(16) float   Vs[256*kHD]; // 12 KB
  int tid = threadIdx.x;
  long base = ((long)b*kS)*kD + h*kHD;
  int k0 = part<<8;
  for (int i=tid;i<256*6;i+=256){ int r=i/6, c=i%6;
    Ks2[i]=*(const __half2*)&K[base+(long)(k0+r)*kD+2*c]; }
  for (int i=tid;i<256*kHD;i+=256){ int r=i/kHD, d=i%kHD;
    Vs[i]=__half2float(V[base+(long)(k0+r)*kD+d]); }
  const float rs = 0.28867513459481287f;
  int q0 = tid, q1 = tid+256;
  __half2 qa2[6], qb2[6];
  {
    const __half2* qp0=(const __half2*)(Q+base+(long)q0*kD);
    const __half2* qp1=(const __half2*)(Q+base+(long)q1*kD);
    #pragma unroll
    for(int c=0;c<6;c++){ qa2[c]=qp0[c]; qb2[c]=qp1[c]; }
  }
  __syncthreads();
  float2 acc0[6], acc1[6];
  #pragma unroll
  for(int j=0;j<6;j++){ acc0[j]=make_float2(0.f,0.f); acc1[j]=make_float2(0.f,0.f); }
  float l0=0.f, l1=0.f;
  for(int k=0;k<256;k++){
    const __half2* kp=Ks2+k*6;
    float sA0=0.f,sA1=0.f,sB0=0.f,sB1=0.f;
    #pragma unroll
    for(int c=0;c<3;c++){
      sA0=fdot2(qa2[2*c],kp[2*c],sA0); sA1=fdot2(qa2[2*c+1],kp[2*c+1],sA1);
      sB0=fdot2(qb2[2*c],kp[2*c],sB0); sB1=fdot2(qb2[2*c+1],kp[2*c+1],sB1);
    }
    float p0=__expf((sA0+sA1)*rs), p1=__expf((sB0+sB1)*rs);
    l0+=p0; l1+=p1;
    const float2* vp=(const float2*)(Vs+k*kHD);
    #pragma unroll
    for(int j=0;j<6;j++){
      float2 v=vp[j];
      acc0[j].x=fmaf(p0,v.x,acc0[j].x); acc0[j].y=fmaf(p0,v.y,acc0[j].y);
      acc1[j].x=fmaf(p1,v.x,acc1[j].x); acc1[j].y=fmaf(p1,v.y,acc1[j].y);
    }
  }
  // self-normalized partials (fp16-safe: |acc/l| <= max|V|)
  float i0=1.f/l0, i1=1.f/l1;
  const long PS=(long)kB*kNH*kS*kHD, LS=(long)kB*kNH*kS;
  long ob=((long)(b*kNH+h))*kS;
  __half2* op0=(__half2*)(OP + part*PS + (ob+q0)*kHD);
  __half2* op1=(__half2*)(OP + part*PS + (ob+q1)*kHD);
  #pragma unroll
  for(int j=0;j<6;j++){
    op0[j]=__floats2half2_rn(acc0[j].x*i0, acc0[j].y*i0);
    op1[j]=__floats2half2_rn(acc1[j].x*i1, acc1[j].y*i1);
  }
  lP[part*LS + ob + q0]=l0;
  lP[part*LS + ob + q1]=l1;
}

// ---------------- K4: o-proj + residual + LN; merges attn partials in staging ----------------
__global__ void __launch_bounds__(256) k_oproj_ln(const float* __restrict__ Xres,
      const __half* __restrict__ OP, const float* __restrict__ lP,
      const float* __restrict__ wo, const float* __restrict__ bo,
      const float* __restrict__ g, const float* __restrict__ bb,
      __half* __restrict__ Xout){
  __shared__ __align__(16) __half W[kD*56];
  __shared__ float bsh[kD], gs[kD], bs2[kD];
  __shared__ __align__(16) float res[32*kD];
  __shared__ __align__(16) __half2 ot2[32*24];
  __shared__ float mrow[32], rstd[32];
  int tid=threadIdx.x;
  for(int i=tid;i<kD*kD;i+=256){ int k=i/48, j=i%48; W[j*56+k]=__float2half(wo[i]); }
  if(tid<kD){ bsh[tid]=bo[tid]; gs[tid]=g[tid]; bs2[tid]=bb[tid]; }
  long row0=(long)blockIdx.x*32;
  // merge the two attn partials: o = (l0*o0 + l1*o1)/(l0+l1)
  const long PS=(long)kB*kNH*kS*kHD, LS=(long)kB*kNH*kS;
  for(int i=tid;i<768;i+=256){
    int r=i/24, c=i%24;
    long gq=row0+r; long bb2=gq>>9; long s=gq&511;
    int h=c/6; int d0=(2*c)%12;
    long li=(bb2*kNH+h)*kS+s;
    float l0=lP[li], l1=lP[li+LS];
    float inv=1.f/(l0+l1);
    long o0=li*(long)kHD+d0;
    float v0=(l0*__half2float(OP[o0  ]) + l1*__half2float(OP[o0  +PS]))*inv;
    float v1=(l0*__half2float(OP[o0+1]) + l1*__half2float(OP[o0+1+PS]))*inv;
    ot2[i]=__floats2half2_rn(v0,v1);
  }
  __syncthreads();
  int r=tid>>3, c0=tid&7;
  __half2 orow[24];
  #pragma unroll
  for(int u=0;u<24;u++) orow[u]=ot2[r*24+u];
  for(int j=c0;j<kD;j+=8){
    float acc=bsh[j]+dot48d(orow, W+j*56);
    res[r*kD+j]=Xres[row0*kD + r*kD + j]+acc;
  }
  __syncthreads();
  if(tid<32){
    float s=0.f, s2=0.f;
    for(int j=0;j<kD;j++){ float v=res[tid*kD+j]; s+=v; s2+=v*v; }
    float m=s*(1.f/kD);
    mrow[tid]=m; rstd[tid]=rsqrtf(s2*(1.f/kD)-m*m+1e-5f);
  }
  __syncthreads();
  for(int i=tid;i<32*kD;i+=256){int r2=i/kD,j=i%kD;
    Xout[row0*kD+i]=__float2half((res[i]-mrow[r2])*rstd[r2]*gs[j]+bs2[j]); }
}

// ---------------- K5: FFN + residual + LN, dot2 ----------------
__global__ void __launch_bounds__(256) k_ffn_ln(const __half* __restrict__ Xin,
   const float* __restrict__ w1, const float* __restrict__ b1,
   const float* __restrict__ w2, const float* __restrict__ b2,
   const float* __restrict__ g, const float* __restrict__ bb,
   float* __restrict__ Xout){
  __shared__ __align__(16) __half W1[kFF*56];
  __shared__ __align__(16) __half W2[kD*136];
  __shared__ float b1s[kFF], b2s[kD], gs[kD], bs2[kD];
  __shared__ __align__(16) __half xt[16*kD];
  __shared__ __align__(16) __half h1h[16*kFF];
  __shared__ __align__(16) float res[16*kD];
  __shared__ float mrow[16], rstd[16];
  int tid=threadIdx.x;
  for(int i=tid;i<kD*kFF;i+=256){ int k=i/128, c=i%128; W1[c*56+k]=__float2half(w1[i]); }
  for(int i=tid;i<kFF*kD;i+=256){ int u=i/48, j=i%48; W2[j*136+u]=__float2half(w2[i]); }
  if(tid<kFF) b1s[tid]=b1[tid];
  if(tid<kD){ b2s[tid]=b2[tid]; gs[tid]=g[tid]; bs2[tid]=bb[tid]; }
  long row0=(long)blockIdx.x*16;
  const __half2* Xp=(const __half2*)(Xin+row0*kD);
  for(int i=tid;i<384;i+=256) ((__half2*)xt)[i]=Xp[i];
  __syncthreads();
  int r=tid>>4, c0=tid&15;
  {
    __half2 xr[24];
    const __half2* xp=(const __half2*)(xt + r*kD);
    #pragma unroll
    for(int u=0;u<24;u++) xr[u]=xp[u];
    for(int c=c0;c<kFF;c+=16){
      float acc=b1s[c]+dot48d(xr, W1+c*56);
      h1h[r*kFF+c]=__float2half(fmaxf(acc,0.f));
    }
  }
  __syncthreads();
  {
    const __half2* hp=(const __half2*)(h1h + r*kFF);
    for(int j=c0;j<kD;j+=16){
      float acc=b2s[j]+dot128d(hp, W2+j*136);
      res[r*kD+j]=__half2float(xt[r*kD+j])+acc;
    }
  }
  __syncthreads();
  if(tid<16){
    float s=0.f, s2=0.f;
    for(int j=0;j<kD;j++){ float v=res[tid*kD+j]; s+=v; s2+=v*v; }
    float m=s*(1.f/kD);
    mrow[tid]=m; rstd[tid]=rsqrtf(s2*(1.f/kD)-m*m+1e-5f);
  }
  __syncthreads();
  for(int i=tid;i<16*kD;i+=256){int r2=i/kD,j=i%kD;
    Xout[row0*kD+i]=(res[i]-mrow[r2])*rstd[r2]*gs[j]+bs2[j]; }
}

// ---------------- K6: cross K/V projection — K row-major [b][s][d], V transposed [b][d][s] ----------------
__global__ void __launch_bounds__(256) k_ckv(const float* __restrict__ M,
    const float* __restrict__ wk, const float* __restrict__ bk,
    const float* __restrict__ wv, const float* __restrict__ bv,
    __half* __restrict__ Kc, __half* __restrict__ Vc){
  __shared__ __align__(16) __half W[2*2688];
  __shared__ float bias[2*kD];
  __shared__ __align__(16) __half2 xt2[32*24];
  int tid=threadIdx.x;
  for(int i=tid;i<2*2304;i+=256){ int m=i/2304, e=i%2304, k=e/48, j=e%48;
    W[m*2688 + j*56 + k] = __float2half((m?wv:wk)[e]); }
  for(int i=tid;i<2*kD;i+=256){ int m=i/kD,e=i%kD; bias[i]=(m?bv:bk)[e]; }
  long row0=(long)blockIdx.x*32;
  const float2* Mp=(const float2*)(M+row0*kD);
  for(int i=tid;i<768;i+=256){ float2 v=Mp[i]; xt2[i]=__floats2half2_rn(v.x,v.y); }
  __syncthreads();
  int r=tid>>3, c0=tid&7;
  __half2 xr[24];
  #pragma unroll
  for(int u=0;u<24;u++) xr[u]=xt2[r*24+u];
  long gr=row0+r; long bb2=gr>>9; long s=gr&511;
  for(int c=c0;c<2*kD;c+=8){
    int m=c/kD, j=c%kD;
    float acc=bias[m*kD+j]+dot48d(xr, W+m*2688+j*56);
    if(m==0) Kc[(bb2*kS+s)*kD + j]=__float2half(acc);     // [b][s][d]
    else     Vc[(bb2*kD+j)*kS + s]=__float2half(acc);     // [b][d][s]
  }
}

// ---------------- K0: decoder weights -> padded FP16, column-major ----------------
// Wh halves: 6 mats 48 cols stride 56: swq@0 swk@2688 swv@5376 swo@8064 cwq@10752
// cwo@13440; w1 128 cols stride 56 @16128; w2 48 cols stride 136 @23296. Tot 29824.
__global__ void k_prep(const float* __restrict__ swq,const float* __restrict__ swk,
                       const float* __restrict__ swv,const float* __restrict__ swo,
                       const float* __restrict__ cwq,const float* __restrict__ cwo,
                       const float* __restrict__ w1,const float* __restrict__ w2,
                       __half* __restrict__ Wh){
  int idx=blockIdx.x*256+threadIdx.x;
  if(idx>=26112) return;
  if(idx<13824){
    int m=idx/2304, e=idx%2304, j=e/48, k=e%48;
    const float* w = (m==0)?swq:((m==1)?swk:((m==2)?swv:((m==3)?swo:((m==4)?cwq:cwo))));
    Wh[m*2688 + j*56 + k] = __float2half(w[k*48+j]);
  } else if(idx<19968){
    int e=idx-13824, c=e/48, k=e%48;
    Wh[16128 + c*56 + k] = __float2half(w1[k*128+c]);
  } else {
    int e=idx-19968, j=e/128, u=e%128;
    Wh[23296 + j*136 + u] = __float2half(w2[u*48+j]);
  }
}

// ---------------- K7: decoder — R17 verbatim (measured best: 230us) ----------------
struct DecP {
  const float *dec_start, *sbq, *sbk, *sbv, *sbo, *ln1g, *ln1b,
              *cbq, *cbo, *ln2g, *ln2b, *fb1, *fb2, *ln3g, *ln3b, *ow, *ob;
};

__global__ void __launch_bounds__(256,1) k_dec(const __half* __restrict__ KT,
    const __half* __restrict__ VT, const __half* __restrict__ Wg, DecP P,
    float* __restrict__ out){
  __shared__ __align__(16) __half Wl[29824];       // fp16 weights, 58.25 KB
  __shared__ __align__(16) float peT[kT*kD];       // PE table, 12 KB
  __shared__ __align__(16) __half KhH[kNH*kT*kHD]; // self-K cache fp16, 6 KB
  __shared__ __align__(16) float  Vh[kNH*kT*kHD];  // self-V cache fp32, 12 KB
  __shared__ __align__(16) __half qSH[kNH*kHD];    // q by head, fp16
  __shared__ __align__(16) float poS[kNH][kD];     // per-wave cross-o-proj partials
  __shared__ __align__(16) __half xvH[kD], soH[kD], h1H[kD], cqH[kD], h2H[kD];
  __shared__ __align__(16) __half f1H[kFF];
  int tid=threadIdx.x, b=blockIdx.x, wave=tid>>6, lane=tid&63;
  const float rs=0.28867513459481287f;

  for(int i=tid;i<29824/8;i+=256) ((float4*)Wl)[i]=((const float4*)Wg)[i];
  for(int i=tid;i<kT*kD;i+=256){ int tt=i/kD, j=i%kD; peT[i]=pe_val(tt,j); }

  // wave0 per-lane constants (wave0 runs every stage except cross-attn)
  float c_sbq=0,c_sbk=0,c_sbv=0, c_bo=0,c_cbq=0,c_cbo=0,c_fb2=0;
  float g1=0,bb1=0,g2=0,bb2=0,g3=0,bb3=0,c_ow=0, c_fb1a=0,c_fb1b=0, c_ds=0;
  if(wave==0){
    if(lane<kD){
      c_ds=P.dec_start[lane];
      c_sbq=P.sbq[lane]; c_sbk=P.sbk[lane]; c_sbv=P.sbv[lane];
      c_bo=P.sbo[lane]; c_cbq=P.cbq[lane]; c_cbo=P.cbo[lane]; c_fb2=P.fb2[lane];
      g1=P.ln1g[lane]; bb1=P.ln1b[lane];
      g2=P.ln2g[lane]; bb2=P.ln2b[lane];
      g3=P.ln3g[lane]; bb3=P.ln3b[lane];
      c_ow=P.ow[lane];
    }
    c_fb1a=P.fb1[lane]; c_fb1b=P.fb1[lane+64];
  }
  float c_ob=P.ob[0];

  // cross-attn K/V resident in registers: head = wave, 4 key-PAIRS per lane
  // Kc layout [b][s][d]; Vc layout [b][d][s] read as half2 pairs along s.
  __half2 Kr2[4][2][6], Vr2[4][kHD];   // 48 + 48 VGPRs
  {
    const __half* Kb = KT + (long)b*kS*kD;
    const __half2* Vb = (const __half2*)VT + (long)b*kD*(kS/2);
    #pragma unroll
    for(int i=0;i<4;i++){
      int sp = lane + 64*i;
      #pragma unroll
      for(int e=0;e<2;e++){
        const __half2* kp=(const __half2*)(Kb + (long)(2*sp+e)*kD + wave*kHD);
        #pragma unroll
        for(int c=0;c<6;c++) Kr2[i][e][c]=kp[c];
      }
      #pragma unroll
      for(int u=0;u<kHD;u++) Vr2[i][u]=Vb[(wave*kHD+u)*(kS/2)+sp];
    }
  }
  __syncthreads();

  // peel t=0's A0: wave0 publishes x0
  float xv=0;
  if(wave==0 && lane<kD){ xv=c_ds+peT[lane]; xvH[lane]=__float2half(xv); }
  __syncthreads();

  float h1=0, h2=0, yacc=0;
  for(int t=0;t<kT;t++){
    // ======== A: wave0-only segment (wsync handoffs, no block barriers) ========
    if(wave==0){
      // A1: qkv — x loaded into regs ONCE, reused across 3 dots
      if(lane<kD){
        __half2 xr[24];
        const __half2* xp=(const __half2*)xvH;
        #pragma unroll
        for(int u=0;u<24;u++) xr[u]=xp[u];
        float qv=c_sbq+dot48d(xr, Wl + 0*2688 + lane*56);
        float kv=c_sbk+dot48d(xr, Wl + 1*2688 + lane*56);
        float vv=c_sbv+dot48d(xr, Wl + 2*2688 + lane*56);
        int hh=lane/kHD, dd=lane%kHD;
        qSH[lane]=__float2half(qv);
        KhH[(hh*kT+t)*kHD+dd]=__float2half(kv);
        Vh[(hh*kT+t)*kHD+dd]=vv;
      }
      wsync();
      // A2: self-attn, 4 heads in one wave: lane = head*16 + keygroup
      {
        int hh=lane>>4, g=lane&15;
        __half2 q2[6];
        const __half2* qp=(const __half2*)qSH + hh*6;
        #pragma unroll
        for(int c=0;c<6;c++) q2[c]=qp[c];
        float l=0.f, acc[kHD];
        #pragma unroll
        for(int u=0;u<kHD;u++) acc[u]=0.f;
        #pragma unroll
        for(int kk=0;kk<4;kk++){
          int key=g+16*kk;
          if(key<=t){
            const __half2* kp=(const __half2*)KhH + (hh*kT+key)*6;
            float a0=0.f,a1=0.f;
            a0=fdot2(q2[0],kp[0],a0); a1=fdot2(q2[1],kp[1],a1);
            a0=fdot2(q2[2],kp[2],a0); a1=fdot2(q2[3],kp[3],a1);
            a0=fdot2(q2[4],kp[4],a0); a1=fdot2(q2[5],kp[5],a1);
            float p=__expf((a0+a1)*rs);
            l+=p;
            const float4* vp=(const float4*)(Vh+(hh*kT+key)*kHD);
            float4 v0=vp[0], v1=vp[1], v2=vp[2];
            float vr[kHD]={v0.x,v0.y,v0.z,v0.w,v1.x,v1.y,v1.z,v1.w,v2.x,v2.y,v2.z,v2.w};
            #pragma unroll
            for(int u=0;u<kHD;u++) acc[u]+=p*vr[u];
          }
        }
        l=rowsum16(l);
        #pragma unroll
        for(int u=0;u<kHD;u++) acc[u]=rowsum16(acc[u]);
        if(g==15){
          float inv=1.f/l;
          #pragma unroll
          for(int u=0;u<6;u++)
            ((__half2*)soH)[hh*6+u]=__floats2half2_rn(acc[2*u]*inv, acc[2*u+1]*inv);
        }
      }
      wsync();
      // A3: self o-proj + residual + LN1
      {
        float rr=0.f;
        if(lane<kD)
          rr=xv+c_bo+dot48d((const __half2*)soH, Wl+8064+lane*56);
        float s1=wsum(rr), s2=wsum(rr*rr);
        float mean=s1*(1.f/48.f);
        float rstd=rsqrtf(s2*(1.f/48.f)-mean*mean+1e-5f);
        h1=0;
        if(lane<kD){ h1=(rr-mean)*rstd*g1+bb1; h1H[lane]=__float2half(h1); }
      }
      wsync();
      // A4: cross-q
      if(lane<kD)
        cqH[lane]=__float2half(c_cbq+dot48d((const __half2*)h1H, Wl+10752+lane*56));
    }
    __syncthreads();                                   // B1: cqH -> all waves
    // ======== X: cross-attn on all 4 waves (head = wave); fp32 P, no max-sub;
    //             ends with per-wave PARTIAL cross-o-proj into poS ========
    {
      __half2 q2[6];
      #pragma unroll
      for(int c=0;c<6;c++) q2[c]=((const __half2*)cqH)[wave*6+c];
      float s[8];
      #pragma unroll
      for(int i=0;i<4;i++){
        #pragma unroll
        for(int e=0;e<2;e++){
          float a0=0.f,a1=0.f;
          const __half2* kp=Kr2[i][e];
          a0=fdot2(q2[0],kp[0],a0); a1=fdot2(q2[1],kp[1],a1);
          a0=fdot2(q2[2],kp[2],a0); a1=fdot2(q2[3],kp[3],a1);
          a0=fdot2(q2[4],kp[4],a0); a1=fdot2(q2[5],kp[5],a1);
          s[2*i+e]=(a0+a1)*rs;
        }
      }
      float p32[8], l=0.f;
      #pragma unroll
      for(int j=0;j<8;j++){ p32[j]=__expf(s[j]); l+=p32[j]; }
      l=wsum(l);
      float inv=1.f/l;
      __half2 ph[4];
      #pragma unroll
      for(int i=0;i<4;i++) ph[i]=__floats2half2_rn(p32[2*i]*inv, p32[2*i+1]*inv);
      float acc[kHD];
      #pragma unroll
      for(int u=0;u<kHD;u++) acc[u]=0.f;
      #pragma unroll
      for(int i=0;i<4;i++){
        #pragma unroll
        for(int u=0;u<kHD;u++) acc[u]=fdot2(ph[i],Vr2[i][u],acc[u]);
      }
      #pragma unroll
      for(int u=0;u<kHD;u++) acc[u]=wsum(acc[u]);
      // partial o-proj for this head (moves dot-work BEFORE barrier B2)
      if(lane<kD){
        __half2 ah[6];
        #pragma unroll
        for(int u=0;u<6;u++) ah[u]=__floats2half2_rn(acc[2*u],acc[2*u+1]);
        const __half2* wp=(const __half2*)(Wl+13440+lane*56+wave*kHD);
        float p0=0.f,p1=0.f;
        p0=fdot2(ah[0],wp[0],p0); p1=fdot2(ah[1],wp[1],p1);
        p0=fdot2(ah[2],wp[2],p0); p1=fdot2(ah[3],wp[3],p1);
        p0=fdot2(ah[4],wp[4],p0); p1=fdot2(ah[5],wp[5],p1);
        poS[wave][lane]=p0+p1;
      }
    }
    __syncthreads();                                   // B2: poS -> wave0
    // ======== C: wave0-only segment ========
    if(wave==0){
      // C0: cross o-proj = sum of 4 per-head partials; + residual + LN2
      {
        float rr=0.f;
        if(lane<kD)
          rr=h1+c_cbo+((poS[0][lane]+poS[1][lane])+(poS[2][lane]+poS[3][lane]));
        float s1=wsum(rr), s2=wsum(rr*rr);
        float mean=s1*(1.f/48.f);
        float rstd=rsqrtf(s2*(1.f/48.f)-mean*mean+1e-5f);
        h2=0;
        if(lane<kD){ h2=(rr-mean)*rstd*g2+bb2; h2H[lane]=__float2half(h2); }
      }
      wsync();
      // C1: FFN1 — 2 cols per lane (pipelined)
      {
        float a=c_fb1a+dot48d((const __half2*)h2H, Wl+16128+lane*56);
        float bcol=c_fb1b+dot48d((const __half2*)h2H, Wl+16128+(lane+64)*56);
        f1H[lane]=__float2half(fmaxf(a,0.f));
        f1H[lane+64]=__float2half(fmaxf(bcol,0.f));
      }
      wsync();
      // C2: FFN2 + residual + LN3; fused next-x publish; y into reg buffer
      {
        float rr=0.f;
        if(lane<kD)
          rr=h2+c_fb2+dot128d((const __half2*)f1H, Wl+23296+lane*136);
        float s1=wsum(rr), s2=wsum(rr*rr);
        float mean=s1*(1.f/48.f);
        float rstd=rsqrtf(s2*(1.f/48.f)-mean*mean+1e-5f);
        float cv=0.f;
        if(lane<kD) cv=(rr-mean)*rstd*g3+bb3;
        // publish x_{t+1} FIRST (hides under the y-reduction)
        if(lane<kD && t+1<kT){ xv=cv+peT[(t+1)*kD+lane]; xvH[lane]=__float2half(xv); }
        wsync();
        float y=wsum(cv*c_ow);
        if(lane==t) yacc=y;
      }
    }
  }
  if(wave==0) out[(long)b*kT+lane]=yacc+c_ob;
}

extern "C" void kernel_launch(void* const* d_in, const int* in_sizes, int n_in,
                              void* d_out, int out_size, void* d_ws, size_t ws_size,
                              hipStream_t stream){
  // ws layout: Wh fp16 (64KB) | A fp32 NB | H1/H2/H3 fp16 NB | OP fp16 2*NB | lP fp32 2*BHS
  // total ~46.2 MB
  float* ws = (float*)d_ws;
  __half* Wh = (__half*)ws;
  const size_t NB = (size_t)kB*kS*kD;     // 3,145,728
  const size_t BHS = (size_t)kB*kNH*kS;   // 262,144
  float*  A  = ws + 16384;
  __half* H1 = (__half*)(A + NB);
  __half* H2 = H1 + NB;
  __half* H3 = H2 + NB;
  __half* OP = H3 + NB;
  float*  lP = (float*)(OP + 2*NB);

  // H1=Q (dead after attn -> Kc); H2=K (dead after attn -> LN1-out); H3=V (dead -> Vc)
  k_qkv  <<<(kB*kS)/32,256,0,stream>>>((const float*)d_in[0],(const float*)d_in[1],(const float*)d_in[2],A,
                                       (const float*)d_in[4],(const float*)d_in[5],(const float*)d_in[6],
                                       (const float*)d_in[7],(const float*)d_in[8],(const float*)d_in[9],H1,H2,H3);
  k_attn <<<kB*kNH*2,256,0,stream>>>(H1,H2,H3,OP,lP);
  k_oproj_ln<<<(kB*kS)/32,256,0,stream>>>(A,OP,lP,(const float*)d_in[10],(const float*)d_in[11],
                                          (const float*)d_in[12],(const float*)d_in[13],H2);
  k_ffn_ln  <<<(kB*kS)/16,256,0,stream>>>(H2,(const float*)d_in[14],(const float*)d_in[15],(const float*)d_in[16],
                                          (const float*)d_in[17],(const float*)d_in[18],(const float*)d_in[19],A);
  k_ckv     <<<(kB*kS)/32,256,0,stream>>>(A,(const float*)d_in[32],(const float*)d_in[33],
                                          (const float*)d_in[34],(const float*)d_in[35],H1,H3);
  k_prep    <<<(26112+255)/256,256,0,stream>>>((const float*)d_in[20],(const float*)d_in[22],(const float*)d_in[24],
                                               (const float*)d_in[26],(const float*)d_in[30],(const float*)d_in[36],
                                               (const float*)d_in[40],(const float*)d_in[42],Wh);
  DecP P;
  P.dec_start=(const float*)d_in[3];
  P.sbq=(const float*)d_in[21]; P.sbk=(const float*)d_in[23]; P.sbv=(const float*)d_in[25]; P.sbo=(const float*)d_in[27];
  P.ln1g=(const float*)d_in[28]; P.ln1b=(const float*)d_in[29];
  P.cbq=(const float*)d_in[31]; P.cbo=(const float*)d_in[37];
  P.ln2g=(const float*)d_in[38]; P.ln2b=(const float*)d_in[39];
  P.fb1=(const float*)d_in[41]; P.fb2=(const float*)d_in[43];
  P.ln3g=(const float*)d_in[44]; P.ln3b=(const float*)d_in[45];
  P.ow=(const float*)d_in[46]; P.ob=(const float*)d_in[47];
  k_dec<<<kB,256,0,stream>>>(H1,H3,Wh,P,(float*)d_out);
}

// Round 10
// 567.276 us; speedup vs baseline: 1.0715x; 1.0071x over previous
//
#include <hip/hip_runtime.h>
#include <hip/hip_bf16.h>
#include <hip/hip_fp16.h>

// Inputs/outputs are FP32 (verified R3/R6).
// R10: KV-in-regs OR weights-in-regs — never both (compiler demotes silently).
// R11: redundant all-wave broadcast stages LOSE. R12: dot2+fp16 LDS; latency-bound.
// R13: wall time = per-step critical path. R14: mega-wave0 + 2 barriers -> 236us.
// R15: weights-in-VGPR regressed. R16: launch gap ~10us/kernel; embed fusion ok.
// R17: encoder mega-fusion regressed; k_dec cross-o-proj partials won.
// R18 lesson: attn 2-way split only -13us -> attn now ISSUE-bound (4 waves/SIMD);
//   k_dec noise band 230-240us (same code, same counters, 10us spread).
// R19: (1) k_prep merged into k_qkv as extra blocks (-1 launch);
//   (2) k_attn issue-diet: K rows padded to 32B -> 2x b128 reads, V as 3x float4
//   (12->5 LDS ops/iter), 1/sqrt(hd) folded into Q at qkv-write (-2 VALU/iter).

constexpr int kB  = 128;
constexpr int kS  = 512;
constexpr int kT  = 64;
constexpr int kD  = 48;
constexpr int kFF = 128;
constexpr int kNH = 4;
constexpr int kHD = 12;

__device__ __forceinline__ void wsync(){
  __builtin_amdgcn_wave_barrier();
  asm volatile("" ::: "memory");
}

// ---- DPP wave64 reductions (VALU-speed) ----
template<int CTRL,int RM,int BM,bool BC>
__device__ __forceinline__ float dppmov(float x, float old){
  return __builtin_bit_cast(float, __builtin_amdgcn_update_dpp(
      __builtin_bit_cast(int, old), __builtin_bit_cast(int, x), CTRL, RM, BM, BC));
}
// sum across 64 lanes, result uniform in all lanes
__device__ __forceinline__ float wsum(float x){
  x += dppmov<0x111,0xf,0xf,true>(x, 0.f);   // row_shr:1
  x += dppmov<0x112,0xf,0xf,true>(x, 0.f);   // row_shr:2
  x += dppmov<0x114,0xf,0xf,true>(x, 0.f);   // row_shr:4
  x += dppmov<0x118,0xf,0xf,true>(x, 0.f);   // row_shr:8
  x += dppmov<0x142,0xa,0xf,true>(x, 0.f);   // row_bcast:15 -> rows 1,3
  x += dppmov<0x143,0xc,0xf,true>(x, 0.f);   // row_bcast:31 -> rows 2,3
  return __builtin_bit_cast(float, __builtin_amdgcn_readlane(__builtin_bit_cast(int, x), 63));
}
// sum within each 16-lane row; result valid at lane 15 of each row
__device__ __forceinline__ float rowsum16(float x){
  x += dppmov<0x111,0xf,0xf,true>(x, 0.f);
  x += dppmov<0x112,0xf,0xf,true>(x, 0.f);
  x += dppmov<0x114,0xf,0xf,true>(x, 0.f);
  x += dppmov<0x118,0xf,0xf,true>(x, 0.f);
  return x;
}

// pe[p, 2i] = sin(p * exp(-2i*ln(10000)/48)), pe[p, 2i+1] = cos(...)
__device__ __forceinline__ float pe_val(int p, int j){   // precise (table init)
  int i = j >> 1;
  float f = expf(-0.19188209108283716f * (float)(2*i));
  float a = (float)p * f;
  return (j & 1) ? cosf(a) : sinf(a);
}
__device__ __forceinline__ float pe_fast(int p, int j){  // encoder embed
  int i = j >> 1;
  float f = __expf(-0.19188209108283716f * (float)(2*i));
  float a = (float)p * f;
  return (j & 1) ? __cosf(a) : __sinf(a);
}

// ---- packed fp16 dot: d = a.x*b.x + a.y*b.y + c (v_dot2_f32_f16) ----
typedef _Float16 h2v __attribute__((ext_vector_type(2)));
union H2U { __half2 h; h2v v; };
__device__ __forceinline__ float fdot2(__half2 a, __half2 b, float c){
#if __has_builtin(__builtin_amdgcn_fdot2)
  H2U ua, ub; ua.h=a; ub.h=b;
  return __builtin_amdgcn_fdot2(ua.v, ub.v, c, false);
#else
  float2 fa=__half22float2(a), fb=__half22float2(b);
  return fmaf(fa.y, fb.y, fmaf(fa.x, fb.x, c));
#endif
}
union F4H2 { float4 f; __half2 h[4]; };

// 48-dot, x (LDS or reg array) vs w (LDS), 4 accumulator chains
__device__ __forceinline__ float dot48d(const __half2* x, const __half* w){
  const __half2* w2=(const __half2*)w;
  float a0=0.f,a1=0.f,a2=0.f,a3=0.f;
  #pragma unroll
  for(int c=0;c<6;c++){
    a0=fdot2(x[4*c+0],w2[4*c+0],a0);
    a1=fdot2(x[4*c+1],w2[4*c+1],a1);
    a2=fdot2(x[4*c+2],w2[4*c+2],a2);
    a3=fdot2(x[4*c+3],w2[4*c+3],a3);
  }
  return (a0+a1)+(a2+a3);
}
// 128-dot, 8 accumulator chains
__device__ __forceinline__ float dot128d(const __half2* x, const __half* w){
  const __half2* w2=(const __half2*)w;
  float a0=0.f,a1=0.f,a2=0.f,a3=0.f,a4=0.f,a5=0.f,a6=0.f,a7=0.f;
  #pragma unroll
  for(int c=0;c<8;c++){
    a0=fdot2(x[8*c+0],w2[8*c+0],a0);
    a1=fdot2(x[8*c+1],w2[8*c+1],a1);
    a2=fdot2(x[8*c+2],w2[8*c+2],a2);
    a3=fdot2(x[8*c+3],w2[8*c+3],a3);
    a4=fdot2(x[8*c+4],w2[8*c+4],a4);
    a5=fdot2(x[8*c+5],w2[8*c+5],a5);
    a6=fdot2(x[8*c+6],w2[8*c+6],a6);
    a7=fdot2(x[8*c+7],w2[8*c+7],a7);
  }
  return ((a0+a1)+(a2+a3))+((a4+a5)+(a6+a7));
}

// ---------------- K2: FUSED embed + encoder QKV projection (+ k_prep blocks) ----------------
// blocks [0,2048): qkv tiles. blocks [2048,2150): decoder weight prep (independent).
__global__ void __launch_bounds__(256) k_qkv(const float* __restrict__ src,
    const float* __restrict__ in_w, const float* __restrict__ in_b,
    float* __restrict__ X0,
    const float* __restrict__ wq, const float* __restrict__ bq,
    const float* __restrict__ wk, const float* __restrict__ bk,
    const float* __restrict__ wv, const float* __restrict__ bv,
    __half* __restrict__ Q, __half* __restrict__ K, __half* __restrict__ V,
    const float* __restrict__ swq, const float* __restrict__ swk,
    const float* __restrict__ swv, const float* __restrict__ swo,
    const float* __restrict__ cwq, const float* __restrict__ cwo,
    const float* __restrict__ dw1, const float* __restrict__ dw2,
    __half* __restrict__ Wh){
  if(blockIdx.x >= 2048){
    // ---- k_prep: decoder weights -> padded fp16 column-major (see Wh map) ----
    int idx=(blockIdx.x-2048)*256+threadIdx.x;
    if(idx>=26112) return;
    if(idx<13824){
      int m=idx/2304, e=idx%2304, j=e/48, k=e%48;
      const float* w = (m==0)?swq:((m==1)?swk:((m==2)?swv:((m==3)?swo:((m==4)?cwq:cwo))));
      Wh[m*2688 + j*56 + k] = __float2half(w[k*48+j]);
    } else if(idx<19968){
      int e=idx-13824, c=e/48, k=e%48;
      Wh[16128 + c*56 + k] = __float2half(dw1[k*128+c]);
    } else {
      int e=idx-19968, j=e/128, u=e%128;
      Wh[23296 + j*136 + u] = __float2half(dw2[u*48+j]);
    }
    return;
  }
  __shared__ __align__(16) __half W[3*2688];     // col stride 56 halves
  __shared__ __align__(16) float bias[3*kD];
  __shared__ __align__(16) __half2 xt2[32*24];
  int tid = threadIdx.x;
  for (int i=tid;i<3*2304;i+=256){ int m=i/2304, e=i%2304, k=e/48, j=e%48;
    const float* w = (m==0)?wq:((m==1)?wk:wv);
    W[m*2688 + j*56 + k] = __float2half(w[e]); }
  for (int i=tid;i<3*kD;i+=256){ int m=i/kD,e=i%kD;
    const float* w=(m==0)?bq:((m==1)?bk:bv); bias[i]=w[e]; }
  long row0 = (long)blockIdx.x*32;
  const float sc = 6.928203230275509f;
  // fused embed: x = (src*in_w+in_b)*sqrt(d) + pe; fp32 -> X0, fp16 -> LDS
  for (int i=tid;i<768;i+=256){
    int r=i/24, c=i%24;
    long gr=row0+r; int s=(int)(gr&511);
    float sv=src[gr];
    float va=(sv*in_w[2*c  ]+in_b[2*c  ])*sc + pe_fast(s,2*c  );
    float vb=(sv*in_w[2*c+1]+in_b[2*c+1])*sc + pe_fast(s,2*c+1);
    ((float2*)X0)[row0*24 + i]=make_float2(va,vb);
    xt2[i]=__floats2half2_rn(va,vb);
  }
  __syncthreads();
  int r = tid>>3, c0 = tid&7;
  __half2 xr[24];
  #pragma unroll
  for(int u=0;u<24;u++) xr[u]=xt2[r*24+u];
  const float rs = 0.28867513459481287f;   // folded into Q (consumed only by attn)
  for (int c=c0; c<3*kD; c+=8){
    int m=c/kD, j=c%kD;
    float acc = bias[m*kD+j] + dot48d(xr, W + m*2688 + j*56);
    if(m==0) acc*=rs;
    __half* o = (m==0)?Q:((m==1)?K:V);
    o[(row0+r)*kD+j]=__float2half(acc);
  }
}

// ---------------- K3: encoder attention — 2-way key split, wide LDS reads ----------------
// grid 1024: blockIdx = (b*kNH+h)*2+part. K rows padded to 8 half2 (32B) -> 2x b128;
// V rows read as 3x float4. Q pre-scaled by 1/sqrt(hd) in k_qkv.
__global__ void __launch_bounds__(256) k_attn(const __half* __restrict__ Q,
      const __half* __restrict__ K, const __half* __restrict__ V,
      __half* __restrict__ OP, float* __restrict__ lP){
  int part = blockIdx.x & 1;
  int bh = blockIdx.x >> 1;
  int b = bh / kNH, h = bh % kNH;
  __shared__ __align__(16) __half2 Ks2[256*8];  // 8 KB (stride 8, cols 6-7 unused)
  __shared__ __align__(16) float   Vs[256*kHD]; // 12 KB
  int tid = threadIdx.x;
  long base = ((long)b*kS)*kD + h*kHD;
  int k0 = part<<8;
  for (int i=tid;i<256*6;i+=256){ int r=i/6, c=i%6;
    Ks2[r*8+c]=*(const __half2*)&K[base+(long)(k0+r)*kD+2*c]; }
  for (int i=tid;i<256*kHD;i+=256){ int r=i/kHD, d=i%kHD;
    Vs[i]=__half2float(V[base+(long)(k0+r)*kD+d]); }
  int q0 = tid, q1 = tid+256;
  __half2 qa2[6], qb2[6];
  {
    const __half2* qp0=(const __half2*)(Q+base+(long)q0*kD);
    const __half2* qp1=(const __half2*)(Q+base+(long)q1*kD);
    #pragma unroll
    for(int c=0;c<6;c++){ qa2[c]=qp0[c]; qb2[c]=qp1[c]; }
  }
  __syncthreads();
  float2 acc0[6], acc1[6];
  #pragma unroll
  for(int j=0;j<6;j++){ acc0[j]=make_float2(0.f,0.f); acc1[j]=make_float2(0.f,0.f); }
  float l0=0.f, l1=0.f;
  for(int k=0;k<256;k++){
    const float4* kp4=(const float4*)(Ks2+k*8);   // broadcast, 2x b128
    F4H2 u0,u1; u0.f=kp4[0]; u1.f=kp4[1];
    float sA0=0.f,sA1=0.f,sB0=0.f,sB1=0.f;
    sA0=fdot2(qa2[0],u0.h[0],sA0); sA1=fdot2(qa2[1],u0.h[1],sA1);
    sA0=fdot2(qa2[2],u0.h[2],sA0); sA1=fdot2(qa2[3],u0.h[3],sA1);
    sA0=fdot2(qa2[4],u1.h[0],sA0); sA1=fdot2(qa2[5],u1.h[1],sA1);
    sB0=fdot2(qb2[0],u0.h[0],sB0); sB1=fdot2(qb2[1],u0.h[1],sB1);
    sB0=fdot2(qb2[2],u0.h[2],sB0); sB1=fdot2(qb2[3],u0.h[3],sB1);
    sB0=fdot2(qb2[4],u1.h[0],sB0); sB1=fdot2(qb2[5],u1.h[1],sB1);
    float p0=__expf(sA0+sA1), p1=__expf(sB0+sB1);
    l0+=p0; l1+=p1;
    const float4* vp=(const float4*)(Vs+k*kHD);   // broadcast, 3x b128
    float4 v0=vp[0], v1=vp[1], v2=vp[2];
    acc0[0].x=fmaf(p0,v0.x,acc0[0].x); acc0[0].y=fmaf(p0,v0.y,acc0[0].y);
    acc0[1].x=fmaf(p0,v0.z,acc0[1].x); acc0[1].y=fmaf(p0,v0.w,acc0[1].y);
    acc0[2].x=fmaf(p0,v1.x,acc0[2].x); acc0[2].y=fmaf(p0,v1.y,acc0[2].y);
    acc0[3].x=fmaf(p0,v1.z,acc0[3].x); acc0[3].y=fmaf(p0,v1.w,acc0[3].y);
    acc0[4].x=fmaf(p0,v2.x,acc0[4].x); acc0[4].y=fmaf(p0,v2.y,acc0[4].y);
    acc0[5].x=fmaf(p0,v2.z,acc0[5].x); acc0[5].y=fmaf(p0,v2.w,acc0[5].y);
    acc1[0].x=fmaf(p1,v0.x,acc1[0].x); acc1[0].y=fmaf(p1,v0.y,acc1[0].y);
    acc1[1].x=fmaf(p1,v0.z,acc1[1].x); acc1[1].y=fmaf(p1,v0.w,acc1[1].y);
    acc1[2].x=fmaf(p1,v1.x,acc1[2].x); acc1[2].y=fmaf(p1,v1.y,acc1[2].y);
    acc1[3].x=fmaf(p1,v1.z,acc1[3].x); acc1[3].y=fmaf(p1,v1.w,acc1[3].y);
    acc1[4].x=fmaf(p1,v2.x,acc1[4].x); acc1[4].y=fmaf(p1,v2.y,acc1[4].y);
    acc1[5].x=fmaf(p1,v2.z,acc1[5].x); acc1[5].y=fmaf(p1,v2.w,acc1[5].y);
  }
  // self-normalized partials (fp16-safe: |acc/l| <= max|V|)
  float i0=1.f/l0, i1=1.f/l1;
  const long PS=(long)kB*kNH*kS*kHD, LS=(long)kB*kNH*kS;
  long ob=((long)(b*kNH+h))*kS;
  __half2* op0=(__half2*)(OP + part*PS + (ob+q0)*kHD);
  __half2* op1=(__half2*)(OP + part*PS + (ob+q1)*kHD);
  #pragma unroll
  for(int j=0;j<6;j++){
    op0[j]=__floats2half2_rn(acc0[j].x*i0, acc0[j].y*i0);
    op1[j]=__floats2half2_rn(acc1[j].x*i1, acc1[j].y*i1);
  }
  lP[part*LS + ob + q0]=l0;
  lP[part*LS + ob + q1]=l1;
}

// ---------------- K4: o-proj + residual + LN; merges attn partials in staging ----------------
__global__ void __launch_bounds__(256) k_oproj_ln(const float* __restrict__ Xres,
      const __half* __restrict__ OP, const float* __restrict__ lP,
      const float* __restrict__ wo, const float* __restrict__ bo,
      const float* __restrict__ g, const float* __restrict__ bb,
      __half* __restrict__ Xout){
  __shared__ __align__(16) __half W[kD*56];
  __shared__ float bsh[kD], gs[kD], bs2[kD];
  __shared__ __align__(16) float res[32*kD];
  __shared__ __align__(16) __half2 ot2[32*24];
  __shared__ float mrow[32], rstd[32];
  int tid=threadIdx.x;
  for(int i=tid;i<kD*kD;i+=256){ int k=i/48, j=i%48; W[j*56+k]=__float2half(wo[i]); }
  if(tid<kD){ bsh[tid]=bo[tid]; gs[tid]=g[tid]; bs2[tid]=bb[tid]; }
  long row0=(long)blockIdx.x*32;
  // merge the two attn partials: o = (l0*o0 + l1*o1)/(l0+l1)
  const long PS=(long)kB*kNH*kS*kHD, LS=(long)kB*kNH*kS;
  for(int i=tid;i<768;i+=256){
    int r=i/24, c=i%24;
    long gq=row0+r; long bb2=gq>>9; long s=gq&511;
    int h=c/6; int d0=(2*c)%12;
    long li=(bb2*kNH+h)*kS+s;
    float l0=lP[li], l1=lP[li+LS];
    float inv=1.f/(l0+l1);
    long o0=li*(long)kHD+d0;
    float v0=(l0*__half2float(OP[o0  ]) + l1*__half2float(OP[o0  +PS]))*inv;
    float v1=(l0*__half2float(OP[o0+1]) + l1*__half2float(OP[o0+1+PS]))*inv;
    ot2[i]=__floats2half2_rn(v0,v1);
  }
  __syncthreads();
  int r=tid>>3, c0=tid&7;
  __half2 orow[24];
  #pragma unroll
  for(int u=0;u<24;u++) orow[u]=ot2[r*24+u];
  for(int j=c0;j<kD;j+=8){
    float acc=bsh[j]+dot48d(orow, W+j*56);
    res[r*kD+j]=Xres[row0*kD + r*kD + j]+acc;
  }
  __syncthreads();
  if(tid<32){
    float s=0.f, s2=0.f;
    for(int j=0;j<kD;j++){ float v=res[tid*kD+j]; s+=v; s2+=v*v; }
    float m=s*(1.f/kD);
    mrow[tid]=m; rstd[tid]=rsqrtf(s2*(1.f/kD)-m*m+1e-5f);
  }
  __syncthreads();
  for(int i=tid;i<32*kD;i+=256){int r2=i/kD,j=i%kD;
    Xout[row0*kD+i]=__float2half((res[i]-mrow[r2])*rstd[r2]*gs[j]+bs2[j]); }
}

// ---------------- K5: FFN + residual + LN, dot2 ----------------
__global__ void __launch_bounds__(256) k_ffn_ln(const __half* __restrict__ Xin,
   const float* __restrict__ w1, const float* __restrict__ b1,
   const float* __restrict__ w2, const float* __restrict__ b2,
   const float* __restrict__ g, const float* __restrict__ bb,
   float* __restrict__ Xout){
  __shared__ __align__(16) __half W1[kFF*56];
  __shared__ __align__(16) __half W2[kD*136];
  __shared__ float b1s[kFF], b2s[kD], gs[kD], bs2[kD];
  __shared__ __align__(16) __half xt[16*kD];
  __shared__ __align__(16) __half h1h[16*kFF];
  __shared__ __align__(16) float res[16*kD];
  __shared__ float mrow[16], rstd[16];
  int tid=threadIdx.x;
  for(int i=tid;i<kD*kFF;i+=256){ int k=i/128, c=i%128; W1[c*56+k]=__float2half(w1[i]); }
  for(int i=tid;i<kFF*kD;i+=256){ int u=i/48, j=i%48; W2[j*136+u]=__float2half(w2[i]); }
  if(tid<kFF) b1s[tid]=b1[tid];
  if(tid<kD){ b2s[tid]=b2[tid]; gs[tid]=g[tid]; bs2[tid]=bb[tid]; }
  long row0=(long)blockIdx.x*16;
  const __half2* Xp=(const __half2*)(Xin+row0*kD);
  for(int i=tid;i<384;i+=256) ((__half2*)xt)[i]=Xp[i];
  __syncthreads();
  int r=tid>>4, c0=tid&15;
  {
    __half2 xr[24];
    const __half2* xp=(const __half2*)(xt + r*kD);
    #pragma unroll
    for(int u=0;u<24;u++) xr[u]=xp[u];
    for(int c=c0;c<kFF;c+=16){
      float acc=b1s[c]+dot48d(xr, W1+c*56);
      h1h[r*kFF+c]=__float2half(fmaxf(acc,0.f));
    }
  }
  __syncthreads();
  {
    const __half2* hp=(const __half2*)(h1h + r*kFF);
    for(int j=c0;j<kD;j+=16){
      float acc=b2s[j]+dot128d(hp, W2+j*136);
      res[r*kD+j]=__half2float(xt[r*kD+j])+acc;
    }
  }
  __syncthreads();
  if(tid<16){
    float s=0.f, s2=0.f;
    for(int j=0;j<kD;j++){ float v=res[tid*kD+j]; s+=v; s2+=v*v; }
    float m=s*(1.f/kD);
    mrow[tid]=m; rstd[tid]=rsqrtf(s2*(1.f/kD)-m*m+1e-5f);
  }
  __syncthreads();
  for(int i=tid;i<16*kD;i+=256){int r2=i/kD,j=i%kD;
    Xout[row0*kD+i]=(res[i]-mrow[r2])*rstd[r2]*gs[j]+bs2[j]; }
}

// ---------------- K6: cross K/V projection — K row-major [b][s][d], V transposed [b][d][s] ----------------
__global__ void __launch_bounds__(256) k_ckv(const float* __restrict__ M,
    const float* __restrict__ wk, const float* __restrict__ bk,
    const float* __restrict__ wv, const float* __restrict__ bv,
    __half* __restrict__ Kc, __half* __restrict__ Vc){
  __shared__ __align__(16) __half W[2*2688];
  __shared__ float bias[2*kD];
  __shared__ __align__(16) __half2 xt2[32*24];
  int tid=threadIdx.x;
  for(int i=tid;i<2*2304;i+=256){ int m=i/2304, e=i%2304, k=e/48, j=e%48;
    W[m*2688 + j*56 + k] = __float2half((m?wv:wk)[e]); }
  for(int i=tid;i<2*kD;i+=256){ int m=i/kD,e=i%kD; bias[i]=(m?bv:bk)[e]; }
  long row0=(long)blockIdx.x*32;
  const float2* Mp=(const float2*)(M+row0*kD);
  for(int i=tid;i<768;i+=256){ float2 v=Mp[i]; xt2[i]=__floats2half2_rn(v.x,v.y); }
  __syncthreads();
  int r=tid>>3, c0=tid&7;
  __half2 xr[24];
  #pragma unroll
  for(int u=0;u<24;u++) xr[u]=xt2[r*24+u];
  long gr=row0+r; long bb2=gr>>9; long s=gr&511;
  for(int c=c0;c<2*kD;c+=8){
    int m=c/kD, j=c%kD;
    float acc=bias[m*kD+j]+dot48d(xr, W+m*2688+j*56);
    if(m==0) Kc[(bb2*kS+s)*kD + j]=__float2half(acc);     // [b][s][d]
    else     Vc[(bb2*kD+j)*kS + s]=__float2half(acc);     // [b][d][s]
  }
}

// ---------------- K7: decoder — R17 structure (measured best; noise band 230-240us) ----------------
struct DecP {
  const float *dec_start, *sbq, *sbk, *sbv, *sbo, *ln1g, *ln1b,
              *cbq, *cbo, *ln2g, *ln2b, *fb1, *fb2, *ln3g, *ln3b, *ow, *ob;
};

__global__ void __launch_bounds__(256,1) k_dec(const __half* __restrict__ KT,
    const __half* __restrict__ VT, const __half* __restrict__ Wg, DecP P,
    float* __restrict__ out){
  __shared__ __align__(16) __half Wl[29824];       // fp16 weights, 58.25 KB
  __shared__ __align__(16) float peT[kT*kD];       // PE table, 12 KB
  __shared__ __align__(16) __half KhH[kNH*kT*kHD]; // self-K cache fp16, 6 KB
  __shared__ __align__(16) float  Vh[kNH*kT*kHD];  // self-V cache fp32, 12 KB
  __shared__ __align__(16) __half qSH[kNH*kHD];    // q by head, fp16
  __shared__ __align__(16) float poS[kNH][kD];     // per-wave cross-o-proj partials
  __shared__ __align__(16) __half xvH[kD], soH[kD], h1H[kD], cqH[kD], h2H[kD];
  __shared__ __align__(16) __half f1H[kFF];
  int tid=threadIdx.x, b=blockIdx.x, wave=tid>>6, lane=tid&63;
  const float rs=0.28867513459481287f;

  for(int i=tid;i<29824/8;i+=256) ((float4*)Wl)[i]=((const float4*)Wg)[i];
  for(int i=tid;i<kT*kD;i+=256){ int tt=i/kD, j=i%kD; peT[i]=pe_val(tt,j); }

  // wave0 per-lane constants (wave0 runs every stage except cross-attn)
  float c_sbq=0,c_sbk=0,c_sbv=0, c_bo=0,c_cbq=0,c_cbo=0,c_fb2=0;
  float g1=0,bb1=0,g2=0,bb2=0,g3=0,bb3=0,c_ow=0, c_fb1a=0,c_fb1b=0, c_ds=0;
  if(wave==0){
    if(lane<kD){
      c_ds=P.dec_start[lane];
      c_sbq=P.sbq[lane]; c_sbk=P.sbk[lane]; c_sbv=P.sbv[lane];
      c_bo=P.sbo[lane]; c_cbq=P.cbq[lane]; c_cbo=P.cbo[lane]; c_fb2=P.fb2[lane];
      g1=P.ln1g[lane]; bb1=P.ln1b[lane];
      g2=P.ln2g[lane]; bb2=P.ln2b[lane];
      g3=P.ln3g[lane]; bb3=P.ln3b[lane];
      c_ow=P.ow[lane];
    }
    c_fb1a=P.fb1[lane]; c_fb1b=P.fb1[lane+64];
  }
  float c_ob=P.ob[0];

  // cross-attn K/V resident in registers: head = wave, 4 key-PAIRS per lane
  // Kc layout [b][s][d]; Vc layout [b][d][s] read as half2 pairs along s.
  __half2 Kr2[4][2][6], Vr2[4][kHD];   // 48 + 48 VGPRs
  {
    const __half* Kb = KT + (long)b*kS*kD;
    const __half2* Vb = (const __half2*)VT + (long)b*kD*(kS/2);
    #pragma unroll
    for(int i=0;i<4;i++){
      int sp = lane + 64*i;
      #pragma unroll
      for(int e=0;e<2;e++){
        const __half2* kp=(const __half2*)(Kb + (long)(2*sp+e)*kD + wave*kHD);
        #pragma unroll
        for(int c=0;c<6;c++) Kr2[i][e][c]=kp[c];
      }
      #pragma unroll
      for(int u=0;u<kHD;u++) Vr2[i][u]=Vb[(wave*kHD+u)*(kS/2)+sp];
    }
  }
  __syncthreads();

  // peel t=0's A0: wave0 publishes x0
  float xv=0;
  if(wave==0 && lane<kD){ xv=c_ds+peT[lane]; xvH[lane]=__float2half(xv); }
  __syncthreads();

  float h1=0, h2=0, yacc=0;
  for(int t=0;t<kT;t++){
    // ======== A: wave0-only segment (wsync handoffs, no block barriers) ========
    if(wave==0){
      // A1: qkv — x loaded into regs ONCE, reused across 3 dots
      if(lane<kD){
        __half2 xr[24];
        const __half2* xp=(const __half2*)xvH;
        #pragma unroll
        for(int u=0;u<24;u++) xr[u]=xp[u];
        float qv=c_sbq+dot48d(xr, Wl + 0*2688 + lane*56);
        float kv=c_sbk+dot48d(xr, Wl + 1*2688 + lane*56);
        float vv=c_sbv+dot48d(xr, Wl + 2*2688 + lane*56);
        int hh=lane/kHD, dd=lane%kHD;
        qSH[lane]=__float2half(qv);
        KhH[(hh*kT+t)*kHD+dd]=__float2half(kv);
        Vh[(hh*kT+t)*kHD+dd]=vv;
      }
      wsync();
      // A2: self-attn, 4 heads in one wave: lane = head*16 + keygroup
      {
        int hh=lane>>4, g=lane&15;
        __half2 q2[6];
        const __half2* qp=(const __half2*)qSH + hh*6;
        #pragma unroll
        for(int c=0;c<6;c++) q2[c]=qp[c];
        float l=0.f, acc[kHD];
        #pragma unroll
        for(int u=0;u<kHD;u++) acc[u]=0.f;
        #pragma unroll
        for(int kk=0;kk<4;kk++){
          int key=g+16*kk;
          if(key<=t){
            const __half2* kp=(const __half2*)KhH + (hh*kT+key)*6;
            float a0=0.f,a1=0.f;
            a0=fdot2(q2[0],kp[0],a0); a1=fdot2(q2[1],kp[1],a1);
            a0=fdot2(q2[2],kp[2],a0); a1=fdot2(q2[3],kp[3],a1);
            a0=fdot2(q2[4],kp[4],a0); a1=fdot2(q2[5],kp[5],a1);
            float p=__expf((a0+a1)*rs);
            l+=p;
            const float4* vp=(const float4*)(Vh+(hh*kT+key)*kHD);
            float4 v0=vp[0], v1=vp[1], v2=vp[2];
            float vr[kHD]={v0.x,v0.y,v0.z,v0.w,v1.x,v1.y,v1.z,v1.w,v2.x,v2.y,v2.z,v2.w};
            #pragma unroll
            for(int u=0;u<kHD;u++) acc[u]+=p*vr[u];
          }
        }
        l=rowsum16(l);
        #pragma unroll
        for(int u=0;u<kHD;u++) acc[u]=rowsum16(acc[u]);
        if(g==15){
          float inv=1.f/l;
          #pragma unroll
          for(int u=0;u<6;u++)
            ((__half2*)soH)[hh*6+u]=__floats2half2_rn(acc[2*u]*inv, acc[2*u+1]*inv);
        }
      }
      wsync();
      // A3: self o-proj + residual + LN1
      {
        float rr=0.f;
        if(lane<kD)
          rr=xv+c_bo+dot48d((const __half2*)soH, Wl+8064+lane*56);
        float s1=wsum(rr), s2=wsum(rr*rr);
        float mean=s1*(1.f/48.f);
        float rstd=rsqrtf(s2*(1.f/48.f)-mean*mean+1e-5f);
        h1=0;
        if(lane<kD){ h1=(rr-mean)*rstd*g1+bb1; h1H[lane]=__float2half(h1); }
      }
      wsync();
      // A4: cross-q
      if(lane<kD)
        cqH[lane]=__float2half(c_cbq+dot48d((const __half2*)h1H, Wl+10752+lane*56));
    }
    __syncthreads();                                   // B1: cqH -> all waves
    // ======== X: cross-attn on all 4 waves (head = wave); fp32 P, no max-sub;
    //             ends with per-wave PARTIAL cross-o-proj into poS ========
    {
      __half2 q2[6];
      #pragma unroll
      for(int c=0;c<6;c++) q2[c]=((const __half2*)cqH)[wave*6+c];
      float s[8];
      #pragma unroll
      for(int i=0;i<4;i++){
        #pragma unroll
        for(int e=0;e<2;e++){
          float a0=0.f,a1=0.f;
          const __half2* kp=Kr2[i][e];
          a0=fdot2(q2[0],kp[0],a0); a1=fdot2(q2[1],kp[1],a1);
          a0=fdot2(q2[2],kp[2],a0); a1=fdot2(q2[3],kp[3],a1);
          a0=fdot2(q2[4],kp[4],a0); a1=fdot2(q2[5],kp[5],a1);
          s[2*i+e]=(a0+a1)*rs;
        }
      }
      float p32[8], l=0.f;
      #pragma unroll
      for(int j=0;j<8;j++){ p32[j]=__expf(s[j]); l+=p32[j]; }
      l=wsum(l);
      float inv=1.f/l;
      __half2 ph[4];
      #pragma unroll
      for(int i=0;i<4;i++) ph[i]=__floats2half2_rn(p32[2*i]*inv, p32[2*i+1]*inv);
      float acc[kHD];
      #pragma unroll
      for(int u=0;u<kHD;u++) acc[u]=0.f;
      #pragma unroll
      for(int i=0;i<4;i++){
        #pragma unroll
        for(int u=0;u<kHD;u++) acc[u]=fdot2(ph[i],Vr2[i][u],acc[u]);
      }
      #pragma unroll
      for(int u=0;u<kHD;u++) acc[u]=wsum(acc[u]);
      // partial o-proj for this head (moves dot-work BEFORE barrier B2)
      if(lane<kD){
        __half2 ah[6];
        #pragma unroll
        for(int u=0;u<6;u++) ah[u]=__floats2half2_rn(acc[2*u],acc[2*u+1]);
        const __half2* wp=(const __half2*)(Wl+13440+lane*56+wave*kHD);
        float p0=0.f,p1=0.f;
        p0=fdot2(ah[0],wp[0],p0); p1=fdot2(ah[1],wp[1],p1);
        p0=fdot2(ah[2],wp[2],p0); p1=fdot2(ah[3],wp[3],p1);
        p0=fdot2(ah[4],wp[4],p0); p1=fdot2(ah[5],wp[5],p1);
        poS[wave][lane]=p0+p1;
      }
    }
    __syncthreads();                                   // B2: poS -> wave0
    // ======== C: wave0-only segment ========
    if(wave==0){
      // C0: cross o-proj = sum of 4 per-head partials; + residual + LN2
      {
        float rr=0.f;
        if(lane<kD)
          rr=h1+c_cbo+((poS[0][lane]+poS[1][lane])+(poS[2][lane]+poS[3][lane]));
        float s1=wsum(rr), s2=wsum(rr*rr);
        float mean=s1*(1.f/48.f);
        float rstd=rsqrtf(s2*(1.f/48.f)-mean*mean+1e-5f);
        h2=0;
        if(lane<kD){ h2=(rr-mean)*rstd*g2+bb2; h2H[lane]=__float2half(h2); }
      }
      wsync();
      // C1: FFN1 — 2 cols per lane (pipelined)
      {
        float a=c_fb1a+dot48d((const __half2*)h2H, Wl+16128+lane*56);
        float bcol=c_fb1b+dot48d((const __half2*)h2H, Wl+16128+(lane+64)*56);
        f1H[lane]=__float2half(fmaxf(a,0.f));
        f1H[lane+64]=__float2half(fmaxf(bcol,0.f));
      }
      wsync();
      // C2: FFN2 + residual + LN3; fused next-x publish; y into reg buffer
      {
        float rr=0.f;
        if(lane<kD)
          rr=h2+c_fb2+dot128d((const __half2*)f1H, Wl+23296+lane*136);
        float s1=wsum(rr), s2=wsum(rr*rr);
        float mean=s1*(1.f/48.f);
        float rstd=rsqrtf(s2*(1.f/48.f)-mean*mean+1e-5f);
        float cv=0.f;
        if(lane<kD) cv=(rr-mean)*rstd*g3+bb3;
        // publish x_{t+1} FIRST (hides under the y-reduction)
        if(lane<kD && t+1<kT){ xv=cv+peT[(t+1)*kD+lane]; xvH[lane]=__float2half(xv); }
        wsync();
        float y=wsum(cv*c_ow);
        if(lane==t) yacc=y;
      }
    }
  }
  if(wave==0) out[(long)b*kT+lane]=yacc+c_ob;
}

extern "C" void kernel_launch(void* const* d_in, const int* in_sizes, int n_in,
                              void* d_out, int out_size, void* d_ws, size_t ws_size,
                              hipStream_t stream){
  // ws layout: Wh fp16 (64KB) | A fp32 NB | H1/H2/H3 fp16 NB | OP fp16 2*NB | lP fp32 2*BHS
  // total ~46.2 MB
  float* ws = (float*)d_ws;
  __half* Wh = (__half*)ws;
  const size_t NB = (size_t)kB*kS*kD;     // 3,145,728
  const size_t BHS = (size_t)kB*kNH*kS;   // 262,144
  float*  A  = ws + 16384;
  __half* H1 = (__half*)(A + NB);
  __half* H2 = H1 + NB;
  __half* H3 = H2 + NB;
  __half* OP = H3 + NB;
  float*  lP = (float*)(OP + 2*NB);

  // H1=Q (dead after attn -> Kc); H2=K (dead after attn -> LN1-out); H3=V (dead -> Vc)
  k_qkv  <<<2048+102,256,0,stream>>>((const float*)d_in[0],(const float*)d_in[1],(const float*)d_in[2],A,
                                     (const float*)d_in[4],(const float*)d_in[5],(const float*)d_in[6],
                                     (const float*)d_in[7],(const float*)d_in[8],(const float*)d_in[9],H1,H2,H3,
                                     (const float*)d_in[20],(const float*)d_in[22],(const float*)d_in[24],
                                     (const float*)d_in[26],(const float*)d_in[30],(const float*)d_in[36],
                                     (const float*)d_in[40],(const float*)d_in[42],Wh);
  k_attn <<<kB*kNH*2,256,0,stream>>>(H1,H2,H3,OP,lP);
  k_oproj_ln<<<(kB*kS)/32,256,0,stream>>>(A,OP,lP,(const float*)d_in[10],(const float*)d_in[11],
                                          (const float*)d_in[12],(const float*)d_in[13],H2);
  k_ffn_ln  <<<(kB*kS)/16,256,0,stream>>>(H2,(const float*)d_in[14],(const float*)d_in[15],(const float*)d_in[16],
                                          (const float*)d_in[17],(const float*)d_in[18],(const float*)d_in[19],A);
  k_ckv     <<<(kB*kS)/32,256,0,stream>>>(A,(const float*)d_in[32],(const float*)d_in[33],
                                          (const float*)d_in[34],(const float*)d_in[35],H1,H3);
  DecP P;
  P.dec_start=(const float*)d_in[3];
  P.sbq=(const float*)d_in[21]; P.sbk=(const float*)d_in[23]; P.sbv=(const float*)d_in[25]; P.sbo=(const float*)d_in[27];
  P.ln1g=(const float*)d_in[28]; P.ln1b=(const float*)d_in[29];
  P.cbq=(const float*)d_in[31]; P.cbo=(const float*)d_in[37];
  P.ln2g=(const float*)d_in[38]; P.ln2b=(const float*)d_in[39];
  P.fb1=(const float*)d_in[41]; P.fb2=(const float*)d_in[43];
  P.ln3g=(const float*)d_in[44]; P.ln3b=(const float*)d_in[45];
  P.ow=(const float*)d_in[46]; P.ob=(const float*)d_in[47];
  k_dec<<<kB,256,0,stream>>>(H1,H3,Wh,P,(float*)d_out);
}